// Round 15
// baseline (515.376 us; speedup 1.0000x reference)
//
#include <hip/hip_runtime.h>
#include <hip/hip_bf16.h>

constexpr int BB = 4, HH = 64, WW = 64, DMv = 96;
constexpr int DSn = 16, DIv = 192, DTRv = 6, KKv = 4, HIDv = 768;
constexpr int LL = 4096;
constexpr int NC = 32, CHK = LL / NC;       // 32 chunks of 128
constexpr int NR = BB * LL;                 // 16384 rows
constexpr int XDS = 40;                     // padded xdbl row stride (dt 0-5, B 8-23, C 24-39)

constexpr size_t S_xi   = (size_t)BB * LL * DIv;          // 3,145,728
constexpr size_t S_xdbl = (size_t)BB * KKv * LL * XDS;    // 2,621,440
constexpr size_t S_big  = (size_t)BB * KKv * LL * DIv;    // 12,582,912
constexpr size_t S_sp   = (size_t)BB * KKv * NC * DIv * DSn;  // 1,572,864 (= S_xi/2)

__device__ __forceinline__ float sigf(float x) { return 1.f / (1.f + __expf(-x)); }
__device__ __forceinline__ float softp(float x) {
  return (x > 20.f) ? x : __logf(1.f + __expf(x));
}

__device__ __forceinline__ int lmap(int k, int l) {
  int lr = (k & 2) ? (LL - 1 - l) : l;
  return (k & 1) ? (((lr & 63) << 6) | (lr >> 6)) : lr;
}

// Generic 32x32 LDS tile transpose: src[R][C] -> dst[C][R], both coalesced.
__global__ void k_transp(const float* __restrict__ src, float* __restrict__ dst,
                         int R, int C) {
  __shared__ float tile[32][33];
  int r0 = blockIdx.x * 32, c0 = blockIdx.y * 32;
  int t = threadIdx.x;            // 256
  int tc = t & 31, tr = t >> 5;   // tr 0..7
#pragma unroll
  for (int i = 0; i < 4; ++i) {
    int r = r0 + tr + i * 8;
    if (r < R && c0 + tc < C) tile[tr + i * 8][tc] = src[(size_t)r * C + c0 + tc];
  }
  __syncthreads();
#pragma unroll
  for (int i = 0; i < 4; ++i) {
    int c = c0 + tr + i * 8;
    int r = r0 + tc;
    if (c < C && r < R) dst[(size_t)c * R + r] = tile[tc][tr + i * 8];
  }
}

// K0: merged weight prep + x transpose. Blocks 0..383 = weight transposes/wcat;
// blocks 384..1151 = xt (64x32 tiles of x).
__global__ void k_wprep(const float* __restrict__ fiw, const float* __restrict__ opw,
                        const float* __restrict__ fow, const float* __restrict__ in_w,
                        const float* __restrict__ xpw, const float* __restrict__ x,
                        float* __restrict__ fiwT, float* __restrict__ opwT,
                        float* __restrict__ fowT, float* __restrict__ wt,
                        float* __restrict__ wcatT, float* __restrict__ xt) {
  int bx = blockIdx.x, t = threadIdx.x;
  __shared__ float smbuf[32 * 65];
  if (bx >= 384) {  // xt: 64x32 tile transpose of x (96x16384 out)
    int i4 = bx - 384;            // 0..767 = (r-block 0..255) * 3 + kb
    int r0 = (i4 / 3) * 64, k0 = (i4 % 3) * 32;
    float (*tile)[65] = (float(*)[65])smbuf;
#pragma unroll
    for (int ii = 0; ii < 8; ++ii) {
      int i = (t >> 5) + ii * 8, j = t & 31;
      tile[j][i] = x[(size_t)(r0 + i) * 96 + k0 + j];
    }
    __syncthreads();
#pragma unroll
    for (int jj = 0; jj < 8; ++jj) {
      int j = (t >> 6) + jj * 4, i = t & 63;
      xt[(size_t)(k0 + j) * NR + r0 + i] = tile[j][i];
    }
    return;
  }
  if (bx >= 270) {  // wcatT[p][d][76]
    int idx = (bx - 270) * 256 + t;
    if (idx < 2 * 192 * 76) {
      int p = idx / (192 * 76);
      int rem = idx % (192 * 76);
      int d = rem / 76, j = rem % 76;
      int k = (j >= 38 ? 2 : 0) + p;
      int c = (j >= 38) ? j - 38 : j;
      wcatT[idx] = xpw[((size_t)(k * 38 + c)) * DIv + d];
    }
    return;
  }
  const float* src; float* dst; int R, C, r0, c0;
  if (bx < 144)      { src = fiw;  dst = fiwT; R = 768; C = 192; r0 = (bx / 6) * 32;         c0 = (bx % 6) * 32; }
  else if (bx < 162) { int i = bx - 144; src = opw; dst = opwT; R = 96;  C = 192; r0 = (i / 6) * 32;  c0 = (i % 6) * 32; }
  else if (bx < 234) { int i = bx - 162; src = fow; dst = fowT; R = 96;  C = 768; r0 = (i / 24) * 32; c0 = (i % 24) * 32; }
  else               { int i = bx - 234; src = in_w; dst = wt;  R = 384; C = 96;  r0 = (i / 3) * 32;  c0 = (i % 3) * 32; }
  float (*tile)[33] = (float(*)[33])smbuf;
  int tc = t & 31, tr = t >> 5;
#pragma unroll
  for (int i = 0; i < 4; ++i) {
    int r = r0 + tr + i * 8;
    if (r < R && c0 + tc < C) tile[tr + i * 8][tc] = src[(size_t)r * C + c0 + tc];
  }
  __syncthreads();
#pragma unroll
  for (int i = 0; i < 4; ++i) {
    int c = c0 + tr + i * 8;
    int r = r0 + tc;
    if (c < C && r < R) dst[(size_t)c * R + r] = tile[tc][tr + i * 8];
  }
}

// K1: xz = x @ in_proj_w.T via xt/wt. Lane = 4 rows (f4, coalesced), wave-uniform
// scalar weight loads.
__global__ void k_inproj(const float* __restrict__ xt, const float* __restrict__ wt,
                         float* __restrict__ xi, float* __restrict__ z) {
  int t = threadIdx.x;
  int wv = t >> 6, lane = t & 63;
  int rq = blockIdx.x * 256 + wv * 64 + lane;   // float4-row index (row = rq*4)
  int c0 = blockIdx.y * 8;
  const float4* xt4 = (const float4*)xt;
  float4 acc[8];
#pragma unroll
  for (int c = 0; c < 8; ++c) acc[c] = make_float4(0.f, 0.f, 0.f, 0.f);
  for (int k = 0; k < 96; ++k) {
    float4 xv = xt4[(size_t)k * (NR / 4) + rq];
    const float* wr = wt + k * 384 + c0;  // wave-uniform -> s_load
#pragma unroll
    for (int c = 0; c < 8; ++c) {
      float w = wr[c];
      acc[c].x += w * xv.x; acc[c].y += w * xv.y;
      acc[c].z += w * xv.z; acc[c].w += w * xv.w;
    }
  }
  float* dst; int cc;
  if (c0 < DIv) { dst = xi; cc = c0; } else { dst = z; cc = c0 - DIv; }
#pragma unroll
  for (int li = 0; li < 4; ++li) {
    size_t row = (size_t)rq * 4 + li;
    float4 v0, v1;
    v0.x = (&acc[0].x)[li]; v0.y = (&acc[1].x)[li];
    v0.z = (&acc[2].x)[li]; v0.w = (&acc[3].x)[li];
    v1.x = (&acc[4].x)[li]; v1.y = (&acc[5].x)[li];
    v1.z = (&acc[6].x)[li]; v1.w = (&acc[7].x)[li];
    float4* o4 = (float4*)(dst + row * DIv + cc);
    o4[0] = v0; o4[1] = v1;
  }
}

// K2 (tiled): xc = silu(dwconv3x3(xi) + conv_b). 16x16 tile x 32 ch, halo +-1.
constexpr int TW2 = 18;
__global__ void k_dwconv2(const float* __restrict__ xi, const float* __restrict__ cw,
                          const float* __restrict__ cb, float* __restrict__ xc) {
  int tile = blockIdx.x;            // 0..15 (4x4 spatial tiles)
  int cg = blockIdx.y, b = blockIdx.z;
  int t = threadIdx.x;              // 256
  int ti0 = (tile >> 2) * 16, tj0 = (tile & 3) * 16;
  __shared__ float sm[TW2 * TW2 * 32];

  for (int e = t; e < TW2 * TW2 * 32; e += 256) {
    int ec = e & 31;
    int sp = e >> 5;                // 0..323
    int hi = sp / TW2, hj = sp % TW2;
    int gi = ti0 + hi - 1, gj = tj0 + hj - 1;
    float v = 0.f;
    if ((unsigned)gi < (unsigned)HH && (unsigned)gj < (unsigned)WW)
      v = xi[((size_t)b * LL + gi * WW + gj) * DIv + cg * 32 + ec];
    sm[e] = v;
  }

  int c = t & 31;
  int cglob = cg * 32 + c;
  float wc[9];
#pragma unroll
  for (int j = 0; j < 9; ++j) wc[j] = cw[cglob * 9 + j];
  float bv = cb[cglob];
  __syncthreads();

  int s0 = t >> 5;  // 0..7
  for (int i = 0; i < 32; ++i) {
    int p = s0 + (i << 3);          // 0..255
    int r = p >> 4, q = p & 15;
    float s = bv;
#pragma unroll
    for (int di = 0; di < 3; ++di)
#pragma unroll
      for (int dj = 0; dj < 3; ++dj)
        s += sm[((r + di) * TW2 + (q + dj)) * 32 + c] * wc[di * 3 + dj];
    xc[((size_t)b * LL + (ti0 + r) * WW + (tj0 + q)) * DIv + cglob] = s * sigf(s);
  }
}

// K3pre-a: spatial transpose per (d,b): xcTs[d][b][j*64+i] = xcT[d][b][i*64+j]
__global__ void k_spt(const float* __restrict__ xcT, float* __restrict__ xcTs) {
  __shared__ float tile[64][65];
  int d = blockIdx.x >> 2, b = blockIdx.x & 3;
  int t = threadIdx.x;  // 256
  const float* src = xcT + (size_t)d * NR + b * LL;
  float* dst = xcTs + (size_t)d * NR + b * LL;
#pragma unroll
  for (int it = 0; it < 16; ++it) {
    int idx = it * 256 + t;
    tile[idx >> 6][idx & 63] = src[idx];
  }
  __syncthreads();
#pragma unroll
  for (int it = 0; it < 16; ++it) {
    int idx = it * 256 + t;
    dst[idx] = tile[idx & 63][idx >> 6];
  }
}

// K3a: x_dbl via transposed operands; stride-40 layout, zeroes pad cols 6,7.
__global__ void k_xdbl2(const float* __restrict__ xcT, const float* __restrict__ xcTs,
                        const float* __restrict__ wcatT, float* __restrict__ xdbl) {
  int t = threadIdx.x;                  // 256
  int rq = blockIdx.x * 256 + t;        // 0..1023 f4-row within b
  int jg = blockIdx.y;                  // 0..18 -> cols jg*4..jg*4+3
  int pb = blockIdx.z;                  // p*4 + b
  int p = pb >> 2, b = pb & 3;
  const float4* A = (const float4*)(p ? xcTs : xcT);
  const float* wbase = wcatT + (size_t)p * 192 * 76 + jg * 4;
  float4 acc[4];
#pragma unroll
  for (int j = 0; j < 4; ++j) acc[j] = make_float4(0.f, 0.f, 0.f, 0.f);
  for (int d = 0; d < 192; ++d) {
    float4 xv = A[(size_t)d * (NR / 4) + b * 1024 + rq];
    const float* wr = wbase + d * 76;   // wave-uniform -> s_load
#pragma unroll
    for (int j = 0; j < 4; ++j) {
      float w = wr[j];
      acc[j].x += w * xv.x; acc[j].y += w * xv.y;
      acc[j].z += w * xv.z; acc[j].w += w * xv.w;
    }
  }
#pragma unroll
  for (int li = 0; li < 4; ++li) {
    int r = rq * 4 + li;
#pragma unroll
    for (int j = 0; j < 4; ++j) {
      int col = jg * 4 + j;
      int kk = (col >= 38) ? (2 + p) : p;
      int c = (col >= 38) ? col - 38 : col;
      int l = (col >= 38) ? (LL - 1 - r) : r;
      int phys = c + (c >= 6 ? 2 : 0);
      size_t ro = (((size_t)(b * KKv + kk)) * LL + l) * XDS;
      xdbl[ro + phys] = (&acc[j].x)[li];
      if (col == 5) { xdbl[ro + 6] = 0.f; xdbl[ro + 7] = 0.f; }
    }
  }
}

// K4a: chunked scan pass 1. Delta computed in-kernel from staged dt cols.
__global__ void k_scan1(const float* __restrict__ xdbl, const float* __restrict__ xc,
                        const float* __restrict__ alogs, const float* __restrict__ dtw,
                        const float* __restrict__ dtb,
                        float* __restrict__ S, float* __restrict__ P) {
  int bx = blockIdx.x;
  int c = bx / 3, dblk = bx % 3;
  int k = blockIdx.y, b = blockIdx.z;
  int t = threadIdx.x, dl = t >> 2, nq = t & 3;
  int d = dblk * 64 + dl;
  __shared__ float de_s[16][64], xv_s[16][64], bc_s[16][32], dt_s[16][8];
  float A[4];
#pragma unroll
  for (int j = 0; j < 4; ++j)
    A[j] = -__expf(alogs[(size_t)(k * DIv + d) * DSn + nq * 4 + j]);
  int derow = t >> 4, dec0 = (t & 15) * 4;
  float DTW[4][6], DTB[4];
#pragma unroll
  for (int jj = 0; jj < 4; ++jj) {
    int dd = k * DIv + dblk * 64 + dec0 + jj;
    DTB[jj] = dtb[dd];
#pragma unroll
    for (int r2 = 0; r2 < 6; ++r2) DTW[jj][r2] = dtw[(size_t)dd * 6 + r2];
  }
  size_t bkL = (size_t)(b * KKv + k) * LL;
  const float* xq = xdbl + bkL * XDS;
  const float* xcb = xc + (size_t)b * LL * DIv;
  float h[4] = {0.f, 0.f, 0.f, 0.f}, sA[4] = {0.f, 0.f, 0.f, 0.f};
  int l0 = c * CHK;
  for (int tile = 0; tile < CHK / 16; ++tile) {
    int lt = l0 + tile * 16;
    __syncthreads();
    {
      int r = t >> 4, q = t & 15;
      int lc = lmap(k, lt + r);
      *(float4*)&xv_s[r][q * 4] = *(const float4*)(xcb + (size_t)lc * DIv + dblk * 64 + q * 4);
      if (t < 128) {
        int r2 = t >> 3, q2 = t & 7;
        *(float4*)&bc_s[r2][q2 * 4] = *(const float4*)(xq + (size_t)(lt + r2) * XDS + 8 + q2 * 4);
      } else if (t < 160) {
        int i3 = t - 128, r3 = i3 >> 1, half = i3 & 1;
        *(float4*)&dt_s[r3][half * 4] = *(const float4*)(xq + (size_t)(lt + r3) * XDS + half * 4);
      }
    }
    __syncthreads();
    {
#pragma unroll
      for (int jj = 0; jj < 4; ++jj) {
        float s = DTB[jj];
#pragma unroll
        for (int r2 = 0; r2 < 6; ++r2) s += dt_s[derow][r2] * DTW[jj][r2];
        de_s[derow][dec0 + jj] = softp(s);
      }
    }
    __syncthreads();
#pragma unroll
    for (int i2 = 0; i2 < 16; ++i2) {
      float de = de_s[i2][dl];
      float xv = xv_s[i2][dl];
      float4 Bv = *(float4*)&bc_s[i2][nq * 4];
      float db = de * xv;
#pragma unroll
      for (int j = 0; j < 4; ++j) {
        float u = de * A[j];
        sA[j] += u;
        h[j] = h[j] * __expf(u) + db * (&Bv.x)[j];
      }
    }
  }
  size_t o = ((((size_t)(b * KKv + k) * NC + c) * 3 + dblk) * 1024) + (size_t)t * 4;
  float4 hs, ps;
#pragma unroll
  for (int j = 0; j < 4; ++j) { (&hs.x)[j] = h[j]; (&ps.x)[j] = __expf(sA[j]); }
  *(float4*)(S + o) = hs;
  *(float4*)(P + o) = ps;
}

// K4b: sequential chunk combine (float4 per thread). Rewrites S[c] <- Hin[c].
__global__ void k_scan2(float* __restrict__ S, const float* __restrict__ P) {
  int dblk = blockIdx.x, k = blockIdx.y, b = blockIdx.z;
  int t = threadIdx.x;  // 256
  size_t base = (((size_t)(b * KKv + k) * NC) * 3 + dblk) * 1024 + (size_t)t * 4;
  float4 h = make_float4(0.f, 0.f, 0.f, 0.f);
  for (int c = 0; c < NC; ++c) {
    size_t o = base + (size_t)c * 3 * 1024;
    float4 s = *(float4*)(S + o), p = *(float4*)(P + o);
    *(float4*)(S + o) = h;  // Hin for chunk c
    h.x = s.x + p.x * h.x; h.y = s.y + p.y * h.y;
    h.z = s.z + p.z * h.z; h.w = s.w + p.w * h.w;
  }
}

// K4c: chunked scan pass 3 — delta in-kernel; width-4 shuffle for y.
__global__ void k_scan3(const float* __restrict__ xdbl, const float* __restrict__ xc,
                        const float* __restrict__ alogs, const float* __restrict__ dtw,
                        const float* __restrict__ dtb,
                        const float* __restrict__ Hin, float* __restrict__ ys) {
  int bx = blockIdx.x;
  int c = bx / 3, dblk = bx % 3;
  int k = blockIdx.y, b = blockIdx.z;
  int t = threadIdx.x, dl = t >> 2, nq = t & 3;
  int d = dblk * 64 + dl;
  __shared__ float de_s[16][64], xv_s[16][64], bc_s[16][32], dt_s[16][8];
  float A[4];
#pragma unroll
  for (int j = 0; j < 4; ++j)
    A[j] = -__expf(alogs[(size_t)(k * DIv + d) * DSn + nq * 4 + j]);
  int derow = t >> 4, dec0 = (t & 15) * 4;
  float DTW[4][6], DTB[4];
#pragma unroll
  for (int jj = 0; jj < 4; ++jj) {
    int dd = k * DIv + dblk * 64 + dec0 + jj;
    DTB[jj] = dtb[dd];
#pragma unroll
    for (int r2 = 0; r2 < 6; ++r2) DTW[jj][r2] = dtw[(size_t)dd * 6 + r2];
  }
  size_t bkL = (size_t)(b * KKv + k) * LL;
  const float* xq = xdbl + bkL * XDS;
  const float* xcb = xc + (size_t)b * LL * DIv;
  float* yp = ys + bkL * DIv + d;
  size_t o = ((((size_t)(b * KKv + k) * NC + c) * 3 + dblk) * 1024) + (size_t)t * 4;
  float4 h4 = *(const float4*)(Hin + o);
  float h[4] = {h4.x, h4.y, h4.z, h4.w};
  int l0 = c * CHK;
  for (int tile = 0; tile < CHK / 16; ++tile) {
    int lt = l0 + tile * 16;
    __syncthreads();
    {
      int r = t >> 4, q = t & 15;
      int lc = lmap(k, lt + r);
      *(float4*)&xv_s[r][q * 4] = *(const float4*)(xcb + (size_t)lc * DIv + dblk * 64 + q * 4);
      if (t < 128) {
        int r2 = t >> 3, q2 = t & 7;
        *(float4*)&bc_s[r2][q2 * 4] = *(const float4*)(xq + (size_t)(lt + r2) * XDS + 8 + q2 * 4);
      } else if (t < 160) {
        int i3 = t - 128, r3 = i3 >> 1, half = i3 & 1;
        *(float4*)&dt_s[r3][half * 4] = *(const float4*)(xq + (size_t)(lt + r3) * XDS + half * 4);
      }
    }
    __syncthreads();
    {
#pragma unroll
      for (int jj = 0; jj < 4; ++jj) {
        float s = DTB[jj];
#pragma unroll
        for (int r2 = 0; r2 < 6; ++r2) s += dt_s[derow][r2] * DTW[jj][r2];
        de_s[derow][dec0 + jj] = softp(s);
      }
    }
    __syncthreads();
#pragma unroll
    for (int i2 = 0; i2 < 16; ++i2) {
      float de = de_s[i2][dl];
      float xv = xv_s[i2][dl];
      float4 Bv = *(float4*)&bc_s[i2][nq * 4];
      float4 Cv = *(float4*)&bc_s[i2][16 + nq * 4];
      float db = de * xv;
      float p = 0.f;
#pragma unroll
      for (int j = 0; j < 4; ++j) {
        h[j] = h[j] * __expf(de * A[j]) + db * (&Bv.x)[j];
        p += h[j] * (&Cv.x)[j];
      }
      p += __shfl_down(p, 2, 4);
      p += __shfl_down(p, 1, 4);
      if (nq == 0) yp[(size_t)(lt + i2) * DIv] = p;
    }
  }
}

// K5+K6 fused: merge 4 directions + D*x skip, LayerNorm(DI), * silu(z) -> ygt
__global__ void k_comln(const float* __restrict__ ys, const float* __restrict__ xc,
                        const float* __restrict__ Ds, const float* __restrict__ z,
                        const float* __restrict__ g, const float* __restrict__ be,
                        float* __restrict__ out) {
  int bl = blockIdx.x;            // b*L + l
  int b = bl >> 12, l = bl & 4095;
  int t = threadIdx.x;            // 64
  int lT = ((l & 63) << 6) | (l >> 6);
  size_t base = (size_t)b * KKv * LL * DIv;
  const float* r0 = ys + base + (size_t)l * DIv;
  const float* r2 = ys + base + ((size_t)2 * LL + (LL - 1 - l)) * DIv;
  const float* r1 = ys + base + ((size_t)1 * LL + lT) * DIv;
  const float* r3 = ys + base + ((size_t)3 * LL + (LL - 1 - lT)) * DIv;
  const float* xr = xc + ((size_t)b * LL + l) * DIv;
  float v[3];
  float s = 0.f, q = 0.f;
#pragma unroll
  for (int cc = 0; cc < 3; ++cc) {
    int d = t + cc * 64;
    float sd = Ds[d] + Ds[DIv + d] + Ds[2 * DIv + d] + Ds[3 * DIv + d];
    float vv = r0[d] + r2[d] + r1[d] + r3[d] + sd * xr[d];
    v[cc] = vv; s += vv; q += vv * vv;
  }
#pragma unroll
  for (int o = 32; o > 0; o >>= 1) { s += __shfl_xor(s, o, 64); q += __shfl_xor(q, o, 64); }
  float m = s / DIv;
  float var = q / DIv - m * m;
  float rs = rsqrtf(var + 1e-5f);
  const float* zr = z + (size_t)bl * DIv;
  float* orow = out + (size_t)bl * DIv;
#pragma unroll
  for (int cc = 0; cc < 3; ++cc) {
    int d = t + cc * 64;
    float zz = zr[d];
    float val = (v[cc] - m) * rs * g[d] + be[d];
    orow[d] = val * zz * sigf(zz);
  }
}

// K7+K8 fused GEMM off ygtT, float4 rows: y<96 -> ffn_in (8 cols, silu);
// y>=96 -> out_proj (4 cols). Grid (16, 120).
__global__ void k_fgemm2(const float* __restrict__ ygtT, const float* __restrict__ fiwT,
                         const float* __restrict__ bias, const float* __restrict__ opwT,
                         float* __restrict__ hcl, float* __restrict__ out0) {
  int t = threadIdx.x;                    // 256
  int rq = blockIdx.x * 256 + t;          // float4-row index
  int y = blockIdx.y;
  const float4* x4 = (const float4*)ygtT;
  if (y < 96) {
    int c0 = y * 8;
    float4 acc[8];
#pragma unroll
    for (int c = 0; c < 8; ++c) acc[c] = make_float4(0.f, 0.f, 0.f, 0.f);
#pragma unroll 4
    for (int k = 0; k < DIv; ++k) {
      float4 xv = x4[(size_t)k * (NR / 4) + rq];
      const float* wr = fiwT + k * HIDv + c0;  // wave-uniform
#pragma unroll
      for (int c = 0; c < 8; ++c) {
        float w = wr[c];
        acc[c].x += w * xv.x; acc[c].y += w * xv.y;
        acc[c].z += w * xv.z; acc[c].w += w * xv.w;
      }
    }
#pragma unroll
    for (int li = 0; li < 4; ++li) {
      size_t row = (size_t)rq * 4 + li;
#pragma unroll
      for (int cc = 0; cc < 2; ++cc) {
        float4 v;
#pragma unroll
        for (int j = 0; j < 4; ++j) {
          float s = (&acc[cc * 4 + j].x)[li] + bias[c0 + cc * 4 + j];
          (&v.x)[j] = s * sigf(s);
        }
        *(float4*)(hcl + row * HIDv + c0 + cc * 4) = v;
      }
    }
  } else {
    int c0 = (y - 96) * 4;
    float4 acc[4];
#pragma unroll
    for (int c = 0; c < 4; ++c) acc[c] = make_float4(0.f, 0.f, 0.f, 0.f);
#pragma unroll 4
    for (int k = 0; k < DIv; ++k) {
      float4 xv = x4[(size_t)k * (NR / 4) + rq];
      const float* wr = opwT + k * DMv + c0;  // wave-uniform
#pragma unroll
      for (int c = 0; c < 4; ++c) {
        float w = wr[c];
        acc[c].x += w * xv.x; acc[c].y += w * xv.y;
        acc[c].z += w * xv.z; acc[c].w += w * xv.w;
      }
    }
#pragma unroll
    for (int li = 0; li < 4; ++li) {
      float4 v;
      v.x = (&acc[0].x)[li]; v.y = (&acc[1].x)[li];
      v.z = (&acc[2].x)[li]; v.w = (&acc[3].x)[li];
      *(float4*)(out0 + ((size_t)rq * 4 + li) * DMv + c0) = v;
    }
  }
}

// K9: fused 5x5 stencil with sliding 5-row register window (6.25 LDS reads/point).
constexpr int TS = 16, CG = 32, TW = TS + 4;  // TW=20
__global__ void k_ffnconv2(const float* __restrict__ hcl, const float* __restrict__ w1,
                           const float* __restrict__ w3, const float* __restrict__ w5,
                           float* __restrict__ hc2) {
  int tile = blockIdx.x;            // 0..15 (4x4 spatial tiles)
  int cg = blockIdx.y, b = blockIdx.z;
  int t = threadIdx.x;              // 256
  int ti0 = (tile >> 2) * TS, tj0 = (tile & 3) * TS;
  __shared__ float sm[TW * TW * CG];

  for (int e = t; e < TW * TW * CG; e += 256) {
    int ec = e & 31;
    int sp = e >> 5;                // 0..399
    int hi = sp / TW, hj = sp % TW;
    int gi = ti0 + hi - 2, gj = tj0 + hj - 2;
    float v = 0.f;
    if ((unsigned)gi < (unsigned)HH && (unsigned)gj < (unsigned)WW)
      v = hcl[((size_t)b * LL + gi * WW + gj) * HIDv + cg * CG + ec];
    sm[e] = v;
  }

  int c = t & 31;
  int cglob = cg * CG + c;
  float wc[25];
#pragma unroll
  for (int di = 0; di < 5; ++di)
#pragma unroll
    for (int dj = 0; dj < 5; ++dj) {
      float w = w5[cglob * 25 + di * 5 + dj];
      if (di >= 1 && di <= 3 && dj >= 1 && dj <= 3)
        w += w3[cglob * 9 + (di - 1) * 3 + (dj - 1)];
      if (di == 2 && dj == 2) w += 1.f + w1[cglob];
      wc[di * 5 + dj] = w;
    }
  __syncthreads();

  int q2 = t >> 5;  // 0..7; thread walks columns q2 and q2+8
#pragma unroll
  for (int half = 0; half < 2; ++half) {
    int q = q2 + half * 8;
    float win[5][5];
#pragma unroll
    for (int di = 0; di < 4; ++di)
#pragma unroll
      for (int dj = 0; dj < 5; ++dj)
        win[di][dj] = sm[(di * TW + (q + dj)) * CG + c];
#pragma unroll
    for (int r = 0; r < 16; ++r) {
      int slot = (r + 4) % 5;
#pragma unroll
      for (int dj = 0; dj < 5; ++dj)
        win[slot][dj] = sm[(((r + 4) * TW) + (q + dj)) * CG + c];
      float s = 0.f;
#pragma unroll
      for (int di = 0; di < 5; ++di) {
        int wsl = (r + di) % 5;
#pragma unroll
        for (int dj = 0; dj < 5; ++dj)
          s += win[wsl][dj] * wc[di * 5 + dj];
      }
      hc2[((size_t)b * LL + (ti0 + r) * WW + (tj0 + q)) * HIDv + cglob] = s;
    }
  }
}

// K10: fused LayerNorm(HID) + transpose: hc2[NR][768] -> hnT[768][NR].
__global__ void k_ln2t(const float* __restrict__ hc2, const float* __restrict__ g,
                       const float* __restrict__ be, float* __restrict__ hnT) {
  int r0 = blockIdx.x * 32;
  int t = threadIdx.x;  // 256
  __shared__ float m_[32], rs_[32];
  __shared__ float tile[32][33];
  {
    int r = t >> 3, q = t & 7;
    const float4* row4 = (const float4*)(hc2 + (size_t)(r0 + r) * HIDv);
    float s = 0.f, qq = 0.f;
#pragma unroll
    for (int j = 0; j < 24; ++j) {
      float4 v = row4[q + j * 8];
      s += v.x + v.y + v.z + v.w;
      qq += v.x * v.x + v.y * v.y + v.z * v.z + v.w * v.w;
    }
    s += __shfl_down(s, 4, 8); qq += __shfl_down(qq, 4, 8);
    s += __shfl_down(s, 2, 8); qq += __shfl_down(qq, 2, 8);
    s += __shfl_down(s, 1, 8); qq += __shfl_down(qq, 1, 8);
    if (q == 0) {
      float m = s / HIDv;
      m_[r] = m;
      rs_[r] = rsqrtf(qq / HIDv - m * m + 1e-5f);
    }
  }
  __syncthreads();
  int tc = t & 31, tr = t >> 5;  // tr 0..7
  for (int ch = 0; ch < 24; ++ch) {
    int c0 = ch * 32;
    float gg = g[c0 + tc], bb = be[c0 + tc];
    __syncthreads();
#pragma unroll
    for (int i = 0; i < 4; ++i) {
      int r = tr + i * 8;
      float v = hc2[(size_t)(r0 + r) * HIDv + c0 + tc];
      tile[tc][r] = (v - m_[r]) * rs_[r] * gg + bb;
    }
    __syncthreads();
#pragma unroll
    for (int i = 0; i < 4; ++i) {
      int cr = tr + i * 8;
      hnT[(size_t)(c0 + cr) * NR + r0 + tc] = tile[cr][tc];
    }
  }
}

// K11a: split-K partial GEMM: part[ks][row][c] = sum_{k in seg} hnT*fowT.
__global__ void k_final3(const float* __restrict__ hnT, const float* __restrict__ fowT,
                         float* __restrict__ part) {
  int t = threadIdx.x;                    // 128
  int rq = blockIdx.x * 128 + t;          // f4-row
  int c0 = blockIdx.y * 8;
  int ks = blockIdx.z;                    // 4 segments of 192
  const float4* x4 = (const float4*)hnT;
  float4 acc[8];
#pragma unroll
  for (int c = 0; c < 8; ++c) acc[c] = make_float4(0.f, 0.f, 0.f, 0.f);
  int k0 = ks * 192;
#pragma unroll 4
  for (int k = k0; k < k0 + 192; ++k) {
    float4 xv = x4[(size_t)k * (NR / 4) + rq];
    const float* wr = fowT + k * DMv + c0;  // wave-uniform
#pragma unroll
    for (int c = 0; c < 8; ++c) {
      float w = wr[c];
      acc[c].x += w * xv.x; acc[c].y += w * xv.y;
      acc[c].z += w * xv.z; acc[c].w += w * xv.w;
    }
  }
  float* pb = part + (size_t)ks * NR * DMv;
#pragma unroll
  for (int li = 0; li < 4; ++li) {
    size_t row = (size_t)rq * 4 + li;
#pragma unroll
    for (int cc = 0; cc < 2; ++cc) {
      float4 v;
#pragma unroll
      for (int j = 0; j < 4; ++j) (&v.x)[j] = (&acc[cc * 4 + j].x)[li];
      *(float4*)(pb + row * DMv + c0 + cc * 4) = v;
    }
  }
}

// K11b: dout = out0 + skip*(sum_k part[k] + bias), float4 elementwise.
__global__ void k_finred(const float* __restrict__ part, const float* __restrict__ out0,
                         const float* __restrict__ bias, const float* __restrict__ skip,
                         float* __restrict__ dout) {
  size_t i = (size_t)blockIdx.x * 256 + threadIdx.x;   // f4 index over NR*DMv/4
  int cq = (int)(i % (DMv / 4));
  const float4* p4 = (const float4*)part;
  size_t npart = (size_t)NR * DMv / 4;
  float4 a = p4[i], b2 = p4[i + npart], c2 = p4[i + 2 * npart], d2 = p4[i + 3 * npart];
  float4 o = ((const float4*)out0)[i];
  float4 bi = ((const float4*)bias)[cq];
  float sk = skip[0];
  float4 r;
  r.x = o.x + sk * (a.x + b2.x + c2.x + d2.x + bi.x);
  r.y = o.y + sk * (a.y + b2.y + c2.y + d2.y + bi.y);
  r.z = o.z + sk * (a.z + b2.z + c2.z + d2.z + bi.z);
  r.w = o.w + sk * (a.w + b2.w + c2.w + d2.w + bi.w);
  ((float4*)dout)[i] = r;
}

extern "C" void kernel_launch(void* const* d_in, const int* in_sizes, int n_in,
                              void* d_out, int out_size, void* d_ws, size_t ws_size,
                              hipStream_t stream) {
  const float* x        = (const float*)d_in[0];
  const float* in_w     = (const float*)d_in[1];
  const float* conv_w   = (const float*)d_in[2];
  const float* conv_b   = (const float*)d_in[3];
  const float* xpw      = (const float*)d_in[4];
  const float* dtw      = (const float*)d_in[5];
  const float* dtb      = (const float*)d_in[6];
  const float* alogs    = (const float*)d_in[7];
  const float* Ds       = (const float*)d_in[8];
  const float* ong      = (const float*)d_in[9];
  const float* onb      = (const float*)d_in[10];
  const float* opw      = (const float*)d_in[11];
  const float* fiw      = (const float*)d_in[12];
  const float* fib      = (const float*)d_in[13];
  const float* dw1      = (const float*)d_in[14];
  const float* dw3      = (const float*)d_in[15];
  const float* dw5      = (const float*)d_in[16];
  const float* flg      = (const float*)d_in[17];
  const float* flb      = (const float*)d_in[18];
  const float* fow      = (const float*)d_in[19];
  const float* fob      = (const float*)d_in[20];
  const float* skip     = (const float*)d_in[21];

  // Workspace layout (aliased; ~150 MB)
  float* ws    = (float*)d_ws;
  float* xi    = ws;                 // -> S/P -> ygtT -> part (with z)
  float* z     = xi + S_xi;
  float* xc    = z + S_xi;           // -> ygt
  float* xdbl  = xc + S_xi;          // -> out0
  float* scr   = xdbl + S_xdbl;      // xt scratch -> hcl -> hnT
  float* ys    = scr + S_big;        // xcT/xcTs scratch -> ys -> hc2
  float* wtiny = ys + S_big;         // persistent small weight transposes
  float* fiwT  = wtiny;              // 192*768 = 147456
  float* opwT  = fiwT + 147456;      // 192*96  = 18432
  float* fowT  = opwT + 18432;       // 768*96  = 73728
  float* wcatT = fowT + 73728;       // 2*192*76 = 29184
  float* wt    = wcatT + 29184;      // 96*384  = 36864

  // Merged weight prep + xt transpose (1 dispatch, 1152 blocks)
  float* xt = scr;                   // 96*16384 floats
  k_wprep<<<1152, 256, 0, stream>>>(fiw, opw, fow, in_w, xpw, x,
                                    fiwT, opwT, fowT, wt, wcatT, xt);

  dim3 gip(NR / 1024, 48);
  k_inproj<<<gip, 256, 0, stream>>>(xt, wt, xi, z);

  dim3 gdw(16, DIv / 32, BB);        // 16 tiles x 6 ch-groups x 4
  k_dwconv2<<<gdw, 256, 0, stream>>>(xi, conv_w, conv_b, xc);

  // x_dbl GEMM via transposed operands (xcT/xcTs in ys region, free until k_scan3)
  float* xcT  = ys;                  // 192*16384 = 3,145,728
  float* xcTs = ys + S_xi;           // 3,145,728 (6.3M < S_big)
  k_transp<<<dim3(512, 6), 256, 0, stream>>>(xc, xcT, NR, DIv);
  k_spt<<<DIv * BB, 256, 0, stream>>>(xcT, xcTs);
  dim3 gxd(4, 19, 8);                // rq-blocks x col-groups x (p*4+b)
  k_xdbl2<<<gxd, 256, 0, stream>>>(xcT, xcTs, wcatT, xdbl);

  // Chunked scan (delta fused in): S/P alias xi (dead until ygtT lands there)
  float* Sbuf = xi;                  // S_sp floats
  float* Pbuf = xi + S_sp;           // S_sp floats (S_sp*2 == S_xi exactly)
  dim3 gs13(NC * 3, KKv, BB);        // 1536 blocks, 64d x 4nq threads
  dim3 gs2(3, KKv, BB);              // 48 blocks (tiny)
  k_scan1<<<gs13, 256, 0, stream>>>(xdbl, xc, alogs, dtw, dtb, Sbuf, Pbuf);
  k_scan2<<<gs2, 256, 0, stream>>>(Sbuf, Pbuf);  // S <- Hin
  k_scan3<<<gs13, 256, 0, stream>>>(xdbl, xc, alogs, dtw, dtb, Sbuf, ys);

  // Fused combine + LayerNorm + silu-gate -> ygt
  float* ygt = xc;
  k_comln<<<BB * LL, 64, 0, stream>>>(ys, xc, Ds, z, ong, onb, ygt);

  // Transpose ygt (16384x192 -> 192x16384) into xi (S/P dead)
  float* ygtT = xi;
  k_transp<<<dim3(512, 6), 256, 0, stream>>>(ygt, ygtT, NR, DIv);

  // Fused ffn_in + out_proj GEMM off ygtT (float4 rows)
  float* out0 = xdbl;
  float* hcl = scr;
  dim3 gfg(NR / 1024, 120);          // (16, 120) = 1920 blocks
  k_fgemm2<<<gfg, 256, 0, stream>>>(ygtT, fiwT, fib, opwT, hcl, out0);

  float* hc2 = ys;
  dim3 gc(16, HIDv / CG, BB);        // 16 spatial tiles x 24 ch-groups x 4
  k_ffnconv2<<<gc, 256, 0, stream>>>(hcl, dw1, dw3, dw5, hc2);

  // Fused LayerNorm + transpose: hc2 (ys) -> hnT (scr; hcl dead)
  float* hnT = scr;
  k_ln2t<<<NR / 32, 256, 0, stream>>>(hc2, flg, flb, hnT);

  // Split-K final GEMM: partials in xi+z region (ygtT dead after k_fgemm2)
  float* part = xi;                  // 4 * NR * 96 = 6,291,456 floats (= 2*S_xi)
  dim3 gfn(NR / 512, DMv / 8, 4);    // (32, 12, 4), block 128
  k_final3<<<gfn, 128, 0, stream>>>(hnT, fowT, part);
  k_finred<<<(NR * DMv / 4) / 256, 256, 0, stream>>>(part, out0, fob, skip, (float*)d_out);
}

// Round 16
// 512.129 us; speedup vs baseline: 1.0063x; 1.0063x over previous
//
#include <hip/hip_runtime.h>
#include <hip/hip_bf16.h>

constexpr int BB = 4, HH = 64, WW = 64, DMv = 96;
constexpr int DSn = 16, DIv = 192, DTRv = 6, KKv = 4, HIDv = 768;
constexpr int LL = 4096;
constexpr int NC = 32, CHK = LL / NC;       // 32 chunks of 128
constexpr int NR = BB * LL;                 // 16384 rows
constexpr int XDS = 40;                     // padded xdbl row stride (dt 0-5, B 8-23, C 24-39)

constexpr size_t S_xi   = (size_t)BB * LL * DIv;          // 3,145,728
constexpr size_t S_xdbl = (size_t)BB * KKv * LL * XDS;    // 2,621,440
constexpr size_t S_big  = (size_t)BB * KKv * LL * DIv;    // 12,582,912
constexpr size_t S_sp   = (size_t)BB * KKv * NC * DIv * DSn;  // 1,572,864 (= S_xi/2)

__device__ __forceinline__ float sigf(float x) { return 1.f / (1.f + __expf(-x)); }
__device__ __forceinline__ float softp(float x) {
  return (x > 20.f) ? x : __logf(1.f + __expf(x));
}

__device__ __forceinline__ int lmap(int k, int l) {
  int lr = (k & 2) ? (LL - 1 - l) : l;
  return (k & 1) ? (((lr & 63) << 6) | (lr >> 6)) : lr;
}

// K0: merged weight prep + x transpose. Blocks 0..383 = weight transposes/wcat;
// blocks 384..1151 = xt (64x32 tiles of x).
__global__ void k_wprep(const float* __restrict__ fiw, const float* __restrict__ opw,
                        const float* __restrict__ fow, const float* __restrict__ in_w,
                        const float* __restrict__ xpw, const float* __restrict__ x,
                        float* __restrict__ fiwT, float* __restrict__ opwT,
                        float* __restrict__ fowT, float* __restrict__ wt,
                        float* __restrict__ wcatT, float* __restrict__ xt) {
  int bx = blockIdx.x, t = threadIdx.x;
  __shared__ float smbuf[32 * 65];
  if (bx >= 384) {  // xt: 64x32 tile transpose of x (96x16384 out)
    int i4 = bx - 384;            // 0..767 = (r-block 0..255) * 3 + kb
    int r0 = (i4 / 3) * 64, k0 = (i4 % 3) * 32;
    float (*tile)[65] = (float(*)[65])smbuf;
#pragma unroll
    for (int ii = 0; ii < 8; ++ii) {
      int i = (t >> 5) + ii * 8, j = t & 31;
      tile[j][i] = x[(size_t)(r0 + i) * 96 + k0 + j];
    }
    __syncthreads();
#pragma unroll
    for (int jj = 0; jj < 8; ++jj) {
      int j = (t >> 6) + jj * 4, i = t & 63;
      xt[(size_t)(k0 + j) * NR + r0 + i] = tile[j][i];
    }
    return;
  }
  if (bx >= 270) {  // wcatT[p][d][76]
    int idx = (bx - 270) * 256 + t;
    if (idx < 2 * 192 * 76) {
      int p = idx / (192 * 76);
      int rem = idx % (192 * 76);
      int d = rem / 76, j = rem % 76;
      int k = (j >= 38 ? 2 : 0) + p;
      int c = (j >= 38) ? j - 38 : j;
      wcatT[idx] = xpw[((size_t)(k * 38 + c)) * DIv + d];
    }
    return;
  }
  const float* src; float* dst; int R, C, r0, c0;
  if (bx < 144)      { src = fiw;  dst = fiwT; R = 768; C = 192; r0 = (bx / 6) * 32;         c0 = (bx % 6) * 32; }
  else if (bx < 162) { int i = bx - 144; src = opw; dst = opwT; R = 96;  C = 192; r0 = (i / 6) * 32;  c0 = (i % 6) * 32; }
  else if (bx < 234) { int i = bx - 162; src = fow; dst = fowT; R = 96;  C = 768; r0 = (i / 24) * 32; c0 = (i % 24) * 32; }
  else               { int i = bx - 234; src = in_w; dst = wt;  R = 384; C = 96;  r0 = (i / 3) * 32;  c0 = (i % 3) * 32; }
  float (*tile)[33] = (float(*)[33])smbuf;
  int tc = t & 31, tr = t >> 5;
#pragma unroll
  for (int i = 0; i < 4; ++i) {
    int r = r0 + tr + i * 8;
    if (r < R && c0 + tc < C) tile[tr + i * 8][tc] = src[(size_t)r * C + c0 + tc];
  }
  __syncthreads();
#pragma unroll
  for (int i = 0; i < 4; ++i) {
    int c = c0 + tr + i * 8;
    int r = r0 + tc;
    if (c < C && r < R) dst[(size_t)c * R + r] = tile[tc][tr + i * 8];
  }
}

// K1: xz = x @ in_proj_w.T via xt/wt. Lane = 4 rows (f4, coalesced), wave-uniform
// scalar weight loads.
__global__ void k_inproj(const float* __restrict__ xt, const float* __restrict__ wt,
                         float* __restrict__ xi, float* __restrict__ z) {
  int t = threadIdx.x;
  int wv = t >> 6, lane = t & 63;
  int rq = blockIdx.x * 256 + wv * 64 + lane;   // float4-row index (row = rq*4)
  int c0 = blockIdx.y * 8;
  const float4* xt4 = (const float4*)xt;
  float4 acc[8];
#pragma unroll
  for (int c = 0; c < 8; ++c) acc[c] = make_float4(0.f, 0.f, 0.f, 0.f);
  for (int k = 0; k < 96; ++k) {
    float4 xv = xt4[(size_t)k * (NR / 4) + rq];
    const float* wr = wt + k * 384 + c0;  // wave-uniform -> s_load
#pragma unroll
    for (int c = 0; c < 8; ++c) {
      float w = wr[c];
      acc[c].x += w * xv.x; acc[c].y += w * xv.y;
      acc[c].z += w * xv.z; acc[c].w += w * xv.w;
    }
  }
  float* dst; int cc;
  if (c0 < DIv) { dst = xi; cc = c0; } else { dst = z; cc = c0 - DIv; }
#pragma unroll
  for (int li = 0; li < 4; ++li) {
    size_t row = (size_t)rq * 4 + li;
    float4 v0, v1;
    v0.x = (&acc[0].x)[li]; v0.y = (&acc[1].x)[li];
    v0.z = (&acc[2].x)[li]; v0.w = (&acc[3].x)[li];
    v1.x = (&acc[4].x)[li]; v1.y = (&acc[5].x)[li];
    v1.z = (&acc[6].x)[li]; v1.w = (&acc[7].x)[li];
    float4* o4 = (float4*)(dst + row * DIv + cc);
    o4[0] = v0; o4[1] = v1;
  }
}

// K2 (tiled, fused layouts): xc = silu(dwconv3x3(xi)+b); also emits xcT [d][b][l]
// and xcTs [d][b][spatial-transposed l]. LDS reused (stride-35 retile).
constexpr int TW2 = 18;
__global__ void k_dwconv3(const float* __restrict__ xi, const float* __restrict__ cw,
                          const float* __restrict__ cb, float* __restrict__ xc,
                          float* __restrict__ xcT, float* __restrict__ xcTs) {
  int tile = blockIdx.x;            // 0..15 (4x4 spatial tiles)
  int cg = blockIdx.y, b = blockIdx.z;
  int t = threadIdx.x;              // 256
  int ti0 = (tile >> 2) * 16, tj0 = (tile & 3) * 16;
  __shared__ float sm[TW2 * TW2 * 32];  // 10368 floats; later retiled as [256][35]

  for (int e = t; e < TW2 * TW2 * 32; e += 256) {
    int ec = e & 31;
    int sp = e >> 5;                // 0..323
    int hi = sp / TW2, hj = sp % TW2;
    int gi = ti0 + hi - 1, gj = tj0 + hj - 1;
    float v = 0.f;
    if ((unsigned)gi < (unsigned)HH && (unsigned)gj < (unsigned)WW)
      v = xi[((size_t)b * LL + gi * WW + gj) * DIv + cg * 32 + ec];
    sm[e] = v;
  }

  int c = t & 31, s0 = t >> 5;
  int cglob = cg * 32 + c;
  float wc[9];
#pragma unroll
  for (int j = 0; j < 9; ++j) wc[j] = cw[cglob * 9 + j];
  float bv = cb[cglob];
  __syncthreads();

  float res[32];
  for (int i = 0; i < 32; ++i) {
    int p = s0 + (i << 3);          // 0..255
    int r = p >> 4, q = p & 15;
    float s = bv;
#pragma unroll
    for (int di = 0; di < 3; ++di)
#pragma unroll
      for (int dj = 0; dj < 3; ++dj)
        s += sm[((r + di) * TW2 + (q + dj)) * 32 + c] * wc[di * 3 + dj];
    res[i] = s * sigf(s);
  }
  __syncthreads();
  // Retile results: sm[p*35 + c] (stride-35 -> conflict-free reads)
  for (int i = 0; i < 32; ++i) {
    int p = s0 + (i << 3);
    sm[p * 35 + c] = res[i];
  }
  __syncthreads();
  // Write xc (channel-last, coalesced)
  for (int it = 0; it < 32; ++it) {
    int e = it * 256 + t;
    int p = e >> 5, ec = e & 31;
    int l = (ti0 + (p >> 4)) * WW + tj0 + (p & 15);
    xc[((size_t)b * LL + l) * DIv + cg * 32 + ec] = sm[p * 35 + ec];
  }
  // Write xcT [d][b][l] (64B segments)
  for (int d2 = 0; d2 < 32; ++d2) {
    int l = (ti0 + (t >> 4)) * WW + tj0 + (t & 15);
    xcT[(size_t)(cg * 32 + d2) * NR + b * LL + l] = sm[t * 35 + d2];
  }
  // Write xcTs [d][b][gj*64+gi] (64B segments)
  for (int d2 = 0; d2 < 32; ++d2) {
    int gjo = t >> 4, gio = t & 15;
    int lt2 = (tj0 + gjo) * WW + ti0 + gio;
    int p = gio * 16 + gjo;
    xcTs[(size_t)(cg * 32 + d2) * NR + b * LL + lt2] = sm[p * 35 + d2];
  }
}

// K3a: x_dbl via transposed operands; stride-40 layout, zeroes pad cols 6,7.
__global__ void k_xdbl2(const float* __restrict__ xcT, const float* __restrict__ xcTs,
                        const float* __restrict__ wcatT, float* __restrict__ xdbl) {
  int t = threadIdx.x;                  // 256
  int rq = blockIdx.x * 256 + t;        // 0..1023 f4-row within b
  int jg = blockIdx.y;                  // 0..18 -> cols jg*4..jg*4+3
  int pb = blockIdx.z;                  // p*4 + b
  int p = pb >> 2, b = pb & 3;
  const float4* A = (const float4*)(p ? xcTs : xcT);
  const float* wbase = wcatT + (size_t)p * 192 * 76 + jg * 4;
  float4 acc[4];
#pragma unroll
  for (int j = 0; j < 4; ++j) acc[j] = make_float4(0.f, 0.f, 0.f, 0.f);
  for (int d = 0; d < 192; ++d) {
    float4 xv = A[(size_t)d * (NR / 4) + b * 1024 + rq];
    const float* wr = wbase + d * 76;   // wave-uniform -> s_load
#pragma unroll
    for (int j = 0; j < 4; ++j) {
      float w = wr[j];
      acc[j].x += w * xv.x; acc[j].y += w * xv.y;
      acc[j].z += w * xv.z; acc[j].w += w * xv.w;
    }
  }
#pragma unroll
  for (int li = 0; li < 4; ++li) {
    int r = rq * 4 + li;
#pragma unroll
    for (int j = 0; j < 4; ++j) {
      int col = jg * 4 + j;
      int kk = (col >= 38) ? (2 + p) : p;
      int c = (col >= 38) ? col - 38 : col;
      int l = (col >= 38) ? (LL - 1 - r) : r;
      int phys = c + (c >= 6 ? 2 : 0);
      size_t ro = (((size_t)(b * KKv + kk)) * LL + l) * XDS;
      xdbl[ro + phys] = (&acc[j].x)[li];
      if (col == 5) { xdbl[ro + 6] = 0.f; xdbl[ro + 7] = 0.f; }
    }
  }
}

// K4a: chunked scan pass 1. Delta computed in-kernel from staged dt cols.
__global__ void k_scan1(const float* __restrict__ xdbl, const float* __restrict__ xc,
                        const float* __restrict__ alogs, const float* __restrict__ dtw,
                        const float* __restrict__ dtb,
                        float* __restrict__ S, float* __restrict__ P) {
  int bx = blockIdx.x;
  int c = bx / 3, dblk = bx % 3;
  int k = blockIdx.y, b = blockIdx.z;
  int t = threadIdx.x, dl = t >> 2, nq = t & 3;
  int d = dblk * 64 + dl;
  __shared__ float de_s[16][64], xv_s[16][64], bc_s[16][32], dt_s[16][8];
  float A[4];
#pragma unroll
  for (int j = 0; j < 4; ++j)
    A[j] = -__expf(alogs[(size_t)(k * DIv + d) * DSn + nq * 4 + j]);
  int derow = t >> 4, dec0 = (t & 15) * 4;
  float DTW[4][6], DTB[4];
#pragma unroll
  for (int jj = 0; jj < 4; ++jj) {
    int dd = k * DIv + dblk * 64 + dec0 + jj;
    DTB[jj] = dtb[dd];
#pragma unroll
    for (int r2 = 0; r2 < 6; ++r2) DTW[jj][r2] = dtw[(size_t)dd * 6 + r2];
  }
  size_t bkL = (size_t)(b * KKv + k) * LL;
  const float* xq = xdbl + bkL * XDS;
  const float* xcb = xc + (size_t)b * LL * DIv;
  float h[4] = {0.f, 0.f, 0.f, 0.f}, sA[4] = {0.f, 0.f, 0.f, 0.f};
  int l0 = c * CHK;
  for (int tile = 0; tile < CHK / 16; ++tile) {
    int lt = l0 + tile * 16;
    __syncthreads();
    {
      int r = t >> 4, q = t & 15;
      int lc = lmap(k, lt + r);
      *(float4*)&xv_s[r][q * 4] = *(const float4*)(xcb + (size_t)lc * DIv + dblk * 64 + q * 4);
      if (t < 128) {
        int r2 = t >> 3, q2 = t & 7;
        *(float4*)&bc_s[r2][q2 * 4] = *(const float4*)(xq + (size_t)(lt + r2) * XDS + 8 + q2 * 4);
      } else if (t < 160) {
        int i3 = t - 128, r3 = i3 >> 1, half = i3 & 1;
        *(float4*)&dt_s[r3][half * 4] = *(const float4*)(xq + (size_t)(lt + r3) * XDS + half * 4);
      }
    }
    __syncthreads();
    {
#pragma unroll
      for (int jj = 0; jj < 4; ++jj) {
        float s = DTB[jj];
#pragma unroll
        for (int r2 = 0; r2 < 6; ++r2) s += dt_s[derow][r2] * DTW[jj][r2];
        de_s[derow][dec0 + jj] = softp(s);
      }
    }
    __syncthreads();
#pragma unroll
    for (int i2 = 0; i2 < 16; ++i2) {
      float de = de_s[i2][dl];
      float xv = xv_s[i2][dl];
      float4 Bv = *(float4*)&bc_s[i2][nq * 4];
      float db = de * xv;
#pragma unroll
      for (int j = 0; j < 4; ++j) {
        float u = de * A[j];
        sA[j] += u;
        h[j] = h[j] * __expf(u) + db * (&Bv.x)[j];
      }
    }
  }
  size_t o = ((((size_t)(b * KKv + k) * NC + c) * 3 + dblk) * 1024) + (size_t)t * 4;
  float4 hs, ps;
#pragma unroll
  for (int j = 0; j < 4; ++j) { (&hs.x)[j] = h[j]; (&ps.x)[j] = __expf(sA[j]); }
  *(float4*)(S + o) = hs;
  *(float4*)(P + o) = ps;
}

// K4b: sequential chunk combine (float4 per thread). Rewrites S[c] <- Hin[c].
__global__ void k_scan2(float* __restrict__ S, const float* __restrict__ P) {
  int dblk = blockIdx.x, k = blockIdx.y, b = blockIdx.z;
  int t = threadIdx.x;  // 256
  size_t base = (((size_t)(b * KKv + k) * NC) * 3 + dblk) * 1024 + (size_t)t * 4;
  float4 h = make_float4(0.f, 0.f, 0.f, 0.f);
  for (int c = 0; c < NC; ++c) {
    size_t o = base + (size_t)c * 3 * 1024;
    float4 s = *(float4*)(S + o), p = *(float4*)(P + o);
    *(float4*)(S + o) = h;  // Hin for chunk c
    h.x = s.x + p.x * h.x; h.y = s.y + p.y * h.y;
    h.z = s.z + p.z * h.z; h.w = s.w + p.w * h.w;
  }
}

// K4c: chunked scan pass 3 — delta in-kernel; width-4 shuffle for y.
__global__ void k_scan3(const float* __restrict__ xdbl, const float* __restrict__ xc,
                        const float* __restrict__ alogs, const float* __restrict__ dtw,
                        const float* __restrict__ dtb,
                        const float* __restrict__ Hin, float* __restrict__ ys) {
  int bx = blockIdx.x;
  int c = bx / 3, dblk = bx % 3;
  int k = blockIdx.y, b = blockIdx.z;
  int t = threadIdx.x, dl = t >> 2, nq = t & 3;
  int d = dblk * 64 + dl;
  __shared__ float de_s[16][64], xv_s[16][64], bc_s[16][32], dt_s[16][8];
  float A[4];
#pragma unroll
  for (int j = 0; j < 4; ++j)
    A[j] = -__expf(alogs[(size_t)(k * DIv + d) * DSn + nq * 4 + j]);
  int derow = t >> 4, dec0 = (t & 15) * 4;
  float DTW[4][6], DTB[4];
#pragma unroll
  for (int jj = 0; jj < 4; ++jj) {
    int dd = k * DIv + dblk * 64 + dec0 + jj;
    DTB[jj] = dtb[dd];
#pragma unroll
    for (int r2 = 0; r2 < 6; ++r2) DTW[jj][r2] = dtw[(size_t)dd * 6 + r2];
  }
  size_t bkL = (size_t)(b * KKv + k) * LL;
  const float* xq = xdbl + bkL * XDS;
  const float* xcb = xc + (size_t)b * LL * DIv;
  float* yp = ys + bkL * DIv + d;
  size_t o = ((((size_t)(b * KKv + k) * NC + c) * 3 + dblk) * 1024) + (size_t)t * 4;
  float4 h4 = *(const float4*)(Hin + o);
  float h[4] = {h4.x, h4.y, h4.z, h4.w};
  int l0 = c * CHK;
  for (int tile = 0; tile < CHK / 16; ++tile) {
    int lt = l0 + tile * 16;
    __syncthreads();
    {
      int r = t >> 4, q = t & 15;
      int lc = lmap(k, lt + r);
      *(float4*)&xv_s[r][q * 4] = *(const float4*)(xcb + (size_t)lc * DIv + dblk * 64 + q * 4);
      if (t < 128) {
        int r2 = t >> 3, q2 = t & 7;
        *(float4*)&bc_s[r2][q2 * 4] = *(const float4*)(xq + (size_t)(lt + r2) * XDS + 8 + q2 * 4);
      } else if (t < 160) {
        int i3 = t - 128, r3 = i3 >> 1, half = i3 & 1;
        *(float4*)&dt_s[r3][half * 4] = *(const float4*)(xq + (size_t)(lt + r3) * XDS + half * 4);
      }
    }
    __syncthreads();
    {
#pragma unroll
      for (int jj = 0; jj < 4; ++jj) {
        float s = DTB[jj];
#pragma unroll
        for (int r2 = 0; r2 < 6; ++r2) s += dt_s[derow][r2] * DTW[jj][r2];
        de_s[derow][dec0 + jj] = softp(s);
      }
    }
    __syncthreads();
#pragma unroll
    for (int i2 = 0; i2 < 16; ++i2) {
      float de = de_s[i2][dl];
      float xv = xv_s[i2][dl];
      float4 Bv = *(float4*)&bc_s[i2][nq * 4];
      float4 Cv = *(float4*)&bc_s[i2][16 + nq * 4];
      float db = de * xv;
      float p = 0.f;
#pragma unroll
      for (int j = 0; j < 4; ++j) {
        h[j] = h[j] * __expf(de * A[j]) + db * (&Bv.x)[j];
        p += h[j] * (&Cv.x)[j];
      }
      p += __shfl_down(p, 2, 4);
      p += __shfl_down(p, 1, 4);
      if (nq == 0) yp[(size_t)(lt + i2) * DIv] = p;
    }
  }
}

// K5+K6+transpose fused: merge 4 dirs + D*x, LayerNorm(DI), silu-gate, write ygtT.
// Block = 32 consecutive l; grid NR/32 = 512.
__global__ void k_comlnt(const float* __restrict__ ys, const float* __restrict__ xc,
                         const float* __restrict__ Ds, const float* __restrict__ z,
                         const float* __restrict__ g, const float* __restrict__ be,
                         float* __restrict__ ygtT) {
  int bl0 = blockIdx.x * 32;
  int b = bl0 >> 12, l0 = bl0 & 4095;
  int t = threadIdx.x;              // 256
  __shared__ float vbuf[32 * 193];
  __shared__ float m_[32], rs_[32];
  __shared__ float tile[32][33];
  {
    int grp = t >> 6, lane6 = t & 63;
    size_t base = (size_t)b * KKv * LL * DIv;
#pragma unroll
    for (int i8 = 0; i8 < 8; ++i8) {
      int li = grp + i8 * 4;
      int l = l0 + li;
      int lT = ((l & 63) << 6) | (l >> 6);
      const float* r0 = ys + base + (size_t)l * DIv;
      const float* r2 = ys + base + ((size_t)2 * LL + (LL - 1 - l)) * DIv;
      const float* r1 = ys + base + ((size_t)1 * LL + lT) * DIv;
      const float* r3 = ys + base + ((size_t)3 * LL + (LL - 1 - lT)) * DIv;
      const float* xr = xc + ((size_t)b * LL + l) * DIv;
#pragma unroll
      for (int cc = 0; cc < 3; ++cc) {
        int d = lane6 + cc * 64;
        float sd = Ds[d] + Ds[DIv + d] + Ds[2 * DIv + d] + Ds[3 * DIv + d];
        vbuf[li * 193 + d] = r0[d] + r2[d] + r1[d] + r3[d] + sd * xr[d];
      }
    }
  }
  __syncthreads();
  {
    int r = t >> 3, q = t & 7;
    float s = 0.f, qq = 0.f;
#pragma unroll
    for (int j = 0; j < 24; ++j) {
      float v = vbuf[r * 193 + q + j * 8];
      s += v; qq += v * v;
    }
    s += __shfl_down(s, 4, 8); qq += __shfl_down(qq, 4, 8);
    s += __shfl_down(s, 2, 8); qq += __shfl_down(qq, 2, 8);
    s += __shfl_down(s, 1, 8); qq += __shfl_down(qq, 1, 8);
    if (q == 0) {
      float m = s / DIv;
      m_[r] = m;
      rs_[r] = rsqrtf(qq / DIv - m * m + 1e-5f);
    }
  }
  __syncthreads();
  int tc = t & 31, tr = t >> 5;
  for (int ch = 0; ch < 6; ++ch) {
    int c0 = ch * 32;
    float gg = g[c0 + tc], bb = be[c0 + tc];
    if (ch) __syncthreads();
#pragma unroll
    for (int i = 0; i < 4; ++i) {
      int r = tr + i * 8;
      float v = vbuf[r * 193 + c0 + tc];
      float zz = z[(size_t)(bl0 + r) * DIv + c0 + tc];
      float val = (v - m_[r]) * rs_[r] * gg + bb;
      tile[tc][r] = val * zz * sigf(zz);
    }
    __syncthreads();
#pragma unroll
    for (int i = 0; i < 4; ++i) {
      int cr = tr + i * 8;
      ygtT[(size_t)(c0 + cr) * NR + bl0 + tc] = tile[cr][tc];
    }
  }
}

// K7+K8 fused GEMM off ygtT (float2 rows): y<48 -> ffn_in (16 cols, silu);
// y>=48 -> out_proj (4 cols). Grid (32, 72).
__global__ void k_fgemm(const float* __restrict__ ygtT, const float* __restrict__ fiwT,
                        const float* __restrict__ bias, const float* __restrict__ opwT,
                        float* __restrict__ hcl, float* __restrict__ out0) {
  int t = threadIdx.x;                    // 256
  int r2 = blockIdx.x * 256 + t;          // float2-row index
  int y = blockIdx.y;
  const float2* x2 = (const float2*)ygtT;
  if (y < 48) {
    int c0 = y * 16;
    float2 acc[16];
#pragma unroll
    for (int c = 0; c < 16; ++c) acc[c] = make_float2(0.f, 0.f);
#pragma unroll 4
    for (int k = 0; k < DIv; ++k) {
      float2 xv = x2[(size_t)k * (NR / 2) + r2];
      const float* wr = fiwT + k * HIDv + c0;  // wave-uniform
#pragma unroll
      for (int c = 0; c < 16; ++c) {
        float w = wr[c];
        acc[c].x += w * xv.x; acc[c].y += w * xv.y;
      }
    }
#pragma unroll
    for (int li = 0; li < 2; ++li) {
      size_t row = (size_t)r2 * 2 + li;
#pragma unroll
      for (int cc = 0; cc < 4; ++cc) {
        float4 v;
#pragma unroll
        for (int j = 0; j < 4; ++j) {
          float s = (&acc[cc * 4 + j].x)[li] + bias[c0 + cc * 4 + j];
          (&v.x)[j] = s * sigf(s);
        }
        *(float4*)(hcl + row * HIDv + c0 + cc * 4) = v;
      }
    }
  } else {
    int c0 = (y - 48) * 4;
    float2 acc[4];
#pragma unroll
    for (int c = 0; c < 4; ++c) acc[c] = make_float2(0.f, 0.f);
#pragma unroll 4
    for (int k = 0; k < DIv; ++k) {
      float2 xv = x2[(size_t)k * (NR / 2) + r2];
      const float* wr = opwT + k * DMv + c0;  // wave-uniform
#pragma unroll
      for (int c = 0; c < 4; ++c) {
        float w = wr[c];
        acc[c].x += w * xv.x; acc[c].y += w * xv.y;
      }
    }
#pragma unroll
    for (int li = 0; li < 2; ++li) {
      float4 v;
      v.x = (&acc[0].x)[li]; v.y = (&acc[1].x)[li];
      v.z = (&acc[2].x)[li]; v.w = (&acc[3].x)[li];
      *(float4*)(out0 + ((size_t)r2 * 2 + li) * DMv + c0) = v;
    }
  }
}

// K9: fused 5x5 stencil with sliding 5-row register window.
constexpr int TS = 16, CG = 32, TW = TS + 4;  // TW=20
__global__ void k_ffnconv2(const float* __restrict__ hcl, const float* __restrict__ w1,
                           const float* __restrict__ w3, const float* __restrict__ w5,
                           float* __restrict__ hc2) {
  int tile = blockIdx.x;            // 0..15 (4x4 spatial tiles)
  int cg = blockIdx.y, b = blockIdx.z;
  int t = threadIdx.x;              // 256
  int ti0 = (tile >> 2) * TS, tj0 = (tile & 3) * TS;
  __shared__ float sm[TW * TW * CG];

  for (int e = t; e < TW * TW * CG; e += 256) {
    int ec = e & 31;
    int sp = e >> 5;                // 0..399
    int hi = sp / TW, hj = sp % TW;
    int gi = ti0 + hi - 2, gj = tj0 + hj - 2;
    float v = 0.f;
    if ((unsigned)gi < (unsigned)HH && (unsigned)gj < (unsigned)WW)
      v = hcl[((size_t)b * LL + gi * WW + gj) * HIDv + cg * CG + ec];
    sm[e] = v;
  }

  int c = t & 31;
  int cglob = cg * CG + c;
  float wc[25];
#pragma unroll
  for (int di = 0; di < 5; ++di)
#pragma unroll
    for (int dj = 0; dj < 5; ++dj) {
      float w = w5[cglob * 25 + di * 5 + dj];
      if (di >= 1 && di <= 3 && dj >= 1 && dj <= 3)
        w += w3[cglob * 9 + (di - 1) * 3 + (dj - 1)];
      if (di == 2 && dj == 2) w += 1.f + w1[cglob];
      wc[di * 5 + dj] = w;
    }
  __syncthreads();

  int q2 = t >> 5;  // 0..7; thread walks columns q2 and q2+8
#pragma unroll
  for (int half = 0; half < 2; ++half) {
    int q = q2 + half * 8;
    float win[5][5];
#pragma unroll
    for (int di = 0; di < 4; ++di)
#pragma unroll
      for (int dj = 0; dj < 5; ++dj)
        win[di][dj] = sm[(di * TW + (q + dj)) * CG + c];
#pragma unroll
    for (int r = 0; r < 16; ++r) {
      int slot = (r + 4) % 5;
#pragma unroll
      for (int dj = 0; dj < 5; ++dj)
        win[slot][dj] = sm[(((r + 4) * TW) + (q + dj)) * CG + c];
      float s = 0.f;
#pragma unroll
      for (int di = 0; di < 5; ++di) {
        int wsl = (r + di) % 5;
#pragma unroll
        for (int dj = 0; dj < 5; ++dj)
          s += win[wsl][dj] * wc[di * 5 + dj];
      }
      hc2[((size_t)b * LL + (ti0 + r) * WW + (tj0 + q)) * HIDv + cglob] = s;
    }
  }
}

// K10: fused LayerNorm(HID) + transpose: hc2[NR][768] -> hnT[768][NR].
__global__ void k_ln2t(const float* __restrict__ hc2, const float* __restrict__ g,
                       const float* __restrict__ be, float* __restrict__ hnT) {
  int r0 = blockIdx.x * 32;
  int t = threadIdx.x;  // 256
  __shared__ float m_[32], rs_[32];
  __shared__ float tile[32][33];
  {
    int r = t >> 3, q = t & 7;
    const float4* row4 = (const float4*)(hc2 + (size_t)(r0 + r) * HIDv);
    float s = 0.f, qq = 0.f;
#pragma unroll
    for (int j = 0; j < 24; ++j) {
      float4 v = row4[q + j * 8];
      s += v.x + v.y + v.z + v.w;
      qq += v.x * v.x + v.y * v.y + v.z * v.z + v.w * v.w;
    }
    s += __shfl_down(s, 4, 8); qq += __shfl_down(qq, 4, 8);
    s += __shfl_down(s, 2, 8); qq += __shfl_down(qq, 2, 8);
    s += __shfl_down(s, 1, 8); qq += __shfl_down(qq, 1, 8);
    if (q == 0) {
      float m = s / HIDv;
      m_[r] = m;
      rs_[r] = rsqrtf(qq / HIDv - m * m + 1e-5f);
    }
  }
  __syncthreads();
  int tc = t & 31, tr = t >> 5;  // tr 0..7
  for (int ch = 0; ch < 24; ++ch) {
    int c0 = ch * 32;
    float gg = g[c0 + tc], bb = be[c0 + tc];
    if (ch) __syncthreads();
#pragma unroll
    for (int i = 0; i < 4; ++i) {
      int r = tr + i * 8;
      float v = hc2[(size_t)(r0 + r) * HIDv + c0 + tc];
      tile[tc][r] = (v - m_[r]) * rs_[r] * gg + bb;
    }
    __syncthreads();
#pragma unroll
    for (int i = 0; i < 4; ++i) {
      int cr = tr + i * 8;
      hnT[(size_t)(c0 + cr) * NR + r0 + tc] = tile[cr][tc];
    }
  }
}

// K11a: split-K partial GEMM: part[ks][row][c] = sum_{k in seg} hnT*fowT.
__global__ void k_final3(const float* __restrict__ hnT, const float* __restrict__ fowT,
                         float* __restrict__ part) {
  int t = threadIdx.x;                    // 128
  int rq = blockIdx.x * 128 + t;          // f4-row
  int c0 = blockIdx.y * 8;
  int ks = blockIdx.z;                    // 4 segments of 192
  const float4* x4 = (const float4*)hnT;
  float4 acc[8];
#pragma unroll
  for (int c = 0; c < 8; ++c) acc[c] = make_float4(0.f, 0.f, 0.f, 0.f);
  int k0 = ks * 192;
#pragma unroll 4
  for (int k = k0; k < k0 + 192; ++k) {
    float4 xv = x4[(size_t)k * (NR / 4) + rq];
    const float* wr = fowT + k * DMv + c0;  // wave-uniform
#pragma unroll
    for (int c = 0; c < 8; ++c) {
      float w = wr[c];
      acc[c].x += w * xv.x; acc[c].y += w * xv.y;
      acc[c].z += w * xv.z; acc[c].w += w * xv.w;
    }
  }
  float* pb = part + (size_t)ks * NR * DMv;
#pragma unroll
  for (int li = 0; li < 4; ++li) {
    size_t row = (size_t)rq * 4 + li;
#pragma unroll
    for (int cc = 0; cc < 2; ++cc) {
      float4 v;
#pragma unroll
      for (int j = 0; j < 4; ++j) (&v.x)[j] = (&acc[cc * 4 + j].x)[li];
      *(float4*)(pb + row * DMv + c0 + cc * 4) = v;
    }
  }
}

// K11b: dout = out0 + skip*(sum_k part[k] + bias), float4 elementwise.
__global__ void k_finred(const float* __restrict__ part, const float* __restrict__ out0,
                         const float* __restrict__ bias, const float* __restrict__ skip,
                         float* __restrict__ dout) {
  size_t i = (size_t)blockIdx.x * 256 + threadIdx.x;   // f4 index over NR*DMv/4
  int cq = (int)(i % (DMv / 4));
  const float4* p4 = (const float4*)part;
  size_t npart = (size_t)NR * DMv / 4;
  float4 a = p4[i], b2 = p4[i + npart], c2 = p4[i + 2 * npart], d2 = p4[i + 3 * npart];
  float4 o = ((const float4*)out0)[i];
  float4 bi = ((const float4*)bias)[cq];
  float sk = skip[0];
  float4 r;
  r.x = o.x + sk * (a.x + b2.x + c2.x + d2.x + bi.x);
  r.y = o.y + sk * (a.y + b2.y + c2.y + d2.y + bi.y);
  r.z = o.z + sk * (a.z + b2.z + c2.z + d2.z + bi.z);
  r.w = o.w + sk * (a.w + b2.w + c2.w + d2.w + bi.w);
  ((float4*)dout)[i] = r;
}

extern "C" void kernel_launch(void* const* d_in, const int* in_sizes, int n_in,
                              void* d_out, int out_size, void* d_ws, size_t ws_size,
                              hipStream_t stream) {
  const float* x        = (const float*)d_in[0];
  const float* in_w     = (const float*)d_in[1];
  const float* conv_w   = (const float*)d_in[2];
  const float* conv_b   = (const float*)d_in[3];
  const float* xpw      = (const float*)d_in[4];
  const float* dtw      = (const float*)d_in[5];
  const float* dtb      = (const float*)d_in[6];
  const float* alogs    = (const float*)d_in[7];
  const float* Ds       = (const float*)d_in[8];
  const float* ong      = (const float*)d_in[9];
  const float* onb      = (const float*)d_in[10];
  const float* opw      = (const float*)d_in[11];
  const float* fiw      = (const float*)d_in[12];
  const float* fib      = (const float*)d_in[13];
  const float* dw1      = (const float*)d_in[14];
  const float* dw3      = (const float*)d_in[15];
  const float* dw5      = (const float*)d_in[16];
  const float* flg      = (const float*)d_in[17];
  const float* flb      = (const float*)d_in[18];
  const float* fow      = (const float*)d_in[19];
  const float* fob      = (const float*)d_in[20];
  const float* skip     = (const float*)d_in[21];

  // Workspace layout (aliased; ~150 MB)
  float* ws    = (float*)d_ws;
  float* xi    = ws;                 // -> S/P -> ygtT -> part (with z)
  float* z     = xi + S_xi;
  float* xc    = z + S_xi;
  float* xdbl  = xc + S_xi;          // -> out0
  float* scr   = xdbl + S_xdbl;      // xt scratch -> hcl -> hnT
  float* ys    = scr + S_big;        // xcT/xcTs -> ys -> hc2
  float* wtiny = ys + S_big;         // persistent small weight transposes
  float* fiwT  = wtiny;              // 192*768 = 147456
  float* opwT  = fiwT + 147456;      // 192*96  = 18432
  float* fowT  = opwT + 18432;       // 768*96  = 73728
  float* wcatT = fowT + 73728;       // 2*192*76 = 29184
  float* wt    = wcatT + 29184;      // 96*384  = 36864

  // Merged weight prep + xt transpose (1 dispatch, 1152 blocks)
  float* xt = scr;                   // 96*16384 floats
  k_wprep<<<1152, 256, 0, stream>>>(fiw, opw, fow, in_w, xpw, x,
                                    fiwT, opwT, fowT, wt, wcatT, xt);

  dim3 gip(NR / 1024, 48);
  k_inproj<<<gip, 256, 0, stream>>>(xt, wt, xi, z);

  // Fused dwconv + 3-layout emit (xc, xcT, xcTs); xcT/xcTs in ys region
  float* xcT  = ys;                  // 192*16384 = 3,145,728
  float* xcTs = ys + S_xi;           // 3,145,728 (6.3M < S_big)
  dim3 gdw(16, DIv / 32, BB);        // 16 tiles x 6 ch-groups x 4
  k_dwconv3<<<gdw, 256, 0, stream>>>(xi, conv_w, conv_b, xc, xcT, xcTs);

  dim3 gxd(4, 19, 8);                // rq-blocks x col-groups x (p*4+b)
  k_xdbl2<<<gxd, 256, 0, stream>>>(xcT, xcTs, wcatT, xdbl);

  // Chunked scan (delta fused in): S/P alias xi (dead until ygtT lands there)
  float* Sbuf = xi;                  // S_sp floats
  float* Pbuf = xi + S_sp;           // S_sp floats (S_sp*2 == S_xi exactly)
  dim3 gs13(NC * 3, KKv, BB);        // 1536 blocks, 64d x 4nq threads
  dim3 gs2(3, KKv, BB);              // 48 blocks (tiny)
  k_scan1<<<gs13, 256, 0, stream>>>(xdbl, xc, alogs, dtw, dtb, Sbuf, Pbuf);
  k_scan2<<<gs2, 256, 0, stream>>>(Sbuf, Pbuf);  // S <- Hin
  k_scan3<<<gs13, 256, 0, stream>>>(xdbl, xc, alogs, dtw, dtb, Sbuf, ys);

  // Fused combine + LayerNorm + silu-gate + transpose -> ygtT (into xi; S/P dead)
  float* ygtT = xi;
  k_comlnt<<<NR / 32, 256, 0, stream>>>(ys, xc, Ds, z, ong, onb, ygtT);

  // Fused ffn_in + out_proj GEMM off ygtT (float2 rows)
  float* out0 = xdbl;
  float* hcl = scr;
  dim3 gfg(NR / 512, 72);            // (32, 72) = 2304 blocks
  k_fgemm<<<gfg, 256, 0, stream>>>(ygtT, fiwT, fib, opwT, hcl, out0);

  float* hc2 = ys;
  dim3 gc(16, HIDv / CG, BB);        // 16 spatial tiles x 24 ch-groups x 4
  k_ffnconv2<<<gc, 256, 0, stream>>>(hcl, dw1, dw3, dw5, hc2);

  // Fused LayerNorm + transpose: hc2 (ys) -> hnT (scr; hcl dead)
  float* hnT = scr;
  k_ln2t<<<NR / 32, 256, 0, stream>>>(hc2, flg, flb, hnT);

  // Split-K final GEMM: partials in xi+z region (ygtT dead after k_fgemm)
  float* part = xi;                  // 4 * NR * 96 = 6,291,456 floats (= 2*S_xi)
  dim3 gfn(NR / 512, DMv / 8, 4);    // (32, 12, 4), block 128
  k_final3<<<gfn, 128, 0, stream>>>(hnT, fowT, part);
  k_finred<<<(NR * DMv / 4) / 256, 256, 0, stream>>>(part, out0, fob, skip, (float*)d_out);
}

// Round 18
// 474.239 us; speedup vs baseline: 1.0867x; 1.0799x over previous
//
#include <hip/hip_runtime.h>
#include <hip/hip_bf16.h>

constexpr int BB = 4, HH = 64, WW = 64, DMv = 96;
constexpr int DSn = 16, DIv = 192, DTRv = 6, KKv = 4, HIDv = 768;
constexpr int LL = 4096;
constexpr int NC = 32, CHK = LL / NC;       // 32 chunks of 128
constexpr int NR = BB * LL;                 // 16384 rows
constexpr int XDS = 40;                     // padded xdbl row stride (dt 0-5, B 8-23, C 24-39)

constexpr size_t S_xi   = (size_t)BB * LL * DIv;          // 3,145,728
constexpr size_t S_xdbl = (size_t)BB * KKv * LL * XDS;    // 2,621,440
constexpr size_t S_big  = (size_t)BB * KKv * LL * DIv;    // 12,582,912
constexpr size_t S_sp   = (size_t)BB * KKv * NC * DIv * DSn;  // 1,572,864 (= S_xi/2)

typedef __attribute__((ext_vector_type(8))) short short8;   // 8 bf16 (4 VGPRs)
typedef __attribute__((ext_vector_type(4))) float floatx4;  // MFMA accumulator

__device__ __forceinline__ float sigf(float x) { return 1.f / (1.f + __expf(-x)); }
__device__ __forceinline__ float softp(float x) {
  return (x > 20.f) ? x : __logf(1.f + __expf(x));
}
__device__ __forceinline__ short bfbits(float v) {
  __hip_bfloat16 h = __float2bfloat16(v);
  return *(short*)&h;
}

__device__ __forceinline__ int lmap(int k, int l) {
  int lr = (k & 2) ? (LL - 1 - l) : l;
  return (k & 1) ? (((lr & 63) << 6) | (lr >> 6)) : lr;
}

// K0: merged weight prep + x transpose + bf16 fragment packing of ffn_in_w.
// 0..143 fiwT | 144..161 opwT | 162..233 fowT | 234..269 wt | 270..383 wcat |
// 384..1151 xt | 1152..1223 fiwP (MFMA B-fragments).
__global__ void k_wprep(const float* __restrict__ fiw, const float* __restrict__ opw,
                        const float* __restrict__ fow, const float* __restrict__ in_w,
                        const float* __restrict__ xpw, const float* __restrict__ x,
                        float* __restrict__ fiwT, float* __restrict__ opwT,
                        float* __restrict__ fowT, float* __restrict__ wt,
                        float* __restrict__ wcatT, float* __restrict__ xt,
                        short* __restrict__ fiwP) {
  int bx = blockIdx.x, t = threadIdx.x;
  __shared__ float smbuf[32 * 65];
  if (bx >= 1152) {  // fiwP: frag f = kt*48+ntg; lane entry = 8 bf16
    int f = (bx - 1152) * 4 + (t >> 6);   // 0..287
    int lane = t & 63, ln16 = lane & 15, qd = lane >> 4;
    int kt = f / 48, ntg = f % 48;
    int n = ntg * 16 + ln16;
#pragma unroll
    for (int j = 0; j < 8; ++j) {
      int k = kt * 32 + qd * 8 + j;
      fiwP[(size_t)f * 512 + lane * 8 + j] = bfbits(fiw[(size_t)n * DIv + k]);
    }
    return;
  }
  if (bx >= 384) {  // xt: 64x32 tile transpose of x (96x16384 out)
    int i4 = bx - 384;
    int r0 = (i4 / 3) * 64, k0 = (i4 % 3) * 32;
    float (*tile)[65] = (float(*)[65])smbuf;
#pragma unroll
    for (int ii = 0; ii < 8; ++ii) {
      int i = (t >> 5) + ii * 8, j = t & 31;
      tile[j][i] = x[(size_t)(r0 + i) * 96 + k0 + j];
    }
    __syncthreads();
#pragma unroll
    for (int jj = 0; jj < 8; ++jj) {
      int j = (t >> 6) + jj * 4, i = t & 63;
      xt[(size_t)(k0 + j) * NR + r0 + i] = tile[j][i];
    }
    return;
  }
  if (bx >= 270) {  // wcatT[p][d][76]
    int idx = (bx - 270) * 256 + t;
    if (idx < 2 * 192 * 76) {
      int p = idx / (192 * 76);
      int rem = idx % (192 * 76);
      int d = rem / 76, j = rem % 76;
      int k = (j >= 38 ? 2 : 0) + p;
      int c = (j >= 38) ? j - 38 : j;
      wcatT[idx] = xpw[((size_t)(k * 38 + c)) * DIv + d];
    }
    return;
  }
  const float* src; float* dst; int R, C, r0, c0;
  if (bx < 144)      { src = fiw;  dst = fiwT; R = 768; C = 192; r0 = (bx / 6) * 32;         c0 = (bx % 6) * 32; }
  else if (bx < 162) { int i = bx - 144; src = opw; dst = opwT; R = 96;  C = 192; r0 = (i / 6) * 32;  c0 = (i % 6) * 32; }
  else if (bx < 234) { int i = bx - 162; src = fow; dst = fowT; R = 96;  C = 768; r0 = (i / 24) * 32; c0 = (i % 24) * 32; }
  else               { int i = bx - 234; src = in_w; dst = wt;  R = 384; C = 96;  r0 = (i / 3) * 32;  c0 = (i % 3) * 32; }
  float (*tile)[33] = (float(*)[33])smbuf;
  int tc = t & 31, tr = t >> 5;
#pragma unroll
  for (int i = 0; i < 4; ++i) {
    int r = r0 + tr + i * 8;
    if (r < R && c0 + tc < C) tile[tr + i * 8][tc] = src[(size_t)r * C + c0 + tc];
  }
  __syncthreads();
#pragma unroll
  for (int i = 0; i < 4; ++i) {
    int c = c0 + tr + i * 8;
    int r = r0 + tc;
    if (c < C && r < R) dst[(size_t)c * R + r] = tile[tc][tr + i * 8];
  }
}

// K1: xz = x @ in_proj_w.T via xt/wt.
__global__ void k_inproj(const float* __restrict__ xt, const float* __restrict__ wt,
                         float* __restrict__ xi, float* __restrict__ z) {
  int t = threadIdx.x;
  int wv = t >> 6, lane = t & 63;
  int rq = blockIdx.x * 256 + wv * 64 + lane;
  int c0 = blockIdx.y * 8;
  const float4* xt4 = (const float4*)xt;
  float4 acc[8];
#pragma unroll
  for (int c = 0; c < 8; ++c) acc[c] = make_float4(0.f, 0.f, 0.f, 0.f);
  for (int k = 0; k < 96; ++k) {
    float4 xv = xt4[(size_t)k * (NR / 4) + rq];
    const float* wr = wt + k * 384 + c0;
#pragma unroll
    for (int c = 0; c < 8; ++c) {
      float w = wr[c];
      acc[c].x += w * xv.x; acc[c].y += w * xv.y;
      acc[c].z += w * xv.z; acc[c].w += w * xv.w;
    }
  }
  float* dst; int cc;
  if (c0 < DIv) { dst = xi; cc = c0; } else { dst = z; cc = c0 - DIv; }
#pragma unroll
  for (int li = 0; li < 4; ++li) {
    size_t row = (size_t)rq * 4 + li;
    float4 v0, v1;
    v0.x = (&acc[0].x)[li]; v0.y = (&acc[1].x)[li];
    v0.z = (&acc[2].x)[li]; v0.w = (&acc[3].x)[li];
    v1.x = (&acc[4].x)[li]; v1.y = (&acc[5].x)[li];
    v1.z = (&acc[6].x)[li]; v1.w = (&acc[7].x)[li];
    float4* o4 = (float4*)(dst + row * DIv + cc);
    o4[0] = v0; o4[1] = v1;
  }
}

// K2 (tiled, fused layouts): xc = silu(dwconv3x3(xi)+b); also emits xcT, xcTs.
constexpr int TW2 = 18;
__global__ void k_dwconv3(const float* __restrict__ xi, const float* __restrict__ cw,
                          const float* __restrict__ cb, float* __restrict__ xc,
                          float* __restrict__ xcT, float* __restrict__ xcTs) {
  int tile = blockIdx.x;
  int cg = blockIdx.y, b = blockIdx.z;
  int t = threadIdx.x;
  int ti0 = (tile >> 2) * 16, tj0 = (tile & 3) * 16;
  __shared__ float sm[TW2 * TW2 * 32];

  for (int e = t; e < TW2 * TW2 * 32; e += 256) {
    int ec = e & 31;
    int sp = e >> 5;
    int hi = sp / TW2, hj = sp % TW2;
    int gi = ti0 + hi - 1, gj = tj0 + hj - 1;
    float v = 0.f;
    if ((unsigned)gi < (unsigned)HH && (unsigned)gj < (unsigned)WW)
      v = xi[((size_t)b * LL + gi * WW + gj) * DIv + cg * 32 + ec];
    sm[e] = v;
  }

  int c = t & 31, s0 = t >> 5;
  int cglob = cg * 32 + c;
  float wc[9];
#pragma unroll
  for (int j = 0; j < 9; ++j) wc[j] = cw[cglob * 9 + j];
  float bv = cb[cglob];
  __syncthreads();

  float res[32];
  for (int i = 0; i < 32; ++i) {
    int p = s0 + (i << 3);
    int r = p >> 4, q = p & 15;
    float s = bv;
#pragma unroll
    for (int di = 0; di < 3; ++di)
#pragma unroll
      for (int dj = 0; dj < 3; ++dj)
        s += sm[((r + di) * TW2 + (q + dj)) * 32 + c] * wc[di * 3 + dj];
    res[i] = s * sigf(s);
  }
  __syncthreads();
  for (int i = 0; i < 32; ++i) {
    int p = s0 + (i << 3);
    sm[p * 35 + c] = res[i];
  }
  __syncthreads();
  for (int it = 0; it < 32; ++it) {
    int e = it * 256 + t;
    int p = e >> 5, ec = e & 31;
    int l = (ti0 + (p >> 4)) * WW + tj0 + (p & 15);
    xc[((size_t)b * LL + l) * DIv + cg * 32 + ec] = sm[p * 35 + ec];
  }
  for (int d2 = 0; d2 < 32; ++d2) {
    int l = (ti0 + (t >> 4)) * WW + tj0 + (t & 15);
    xcT[(size_t)(cg * 32 + d2) * NR + b * LL + l] = sm[t * 35 + d2];
  }
  for (int d2 = 0; d2 < 32; ++d2) {
    int gjo = t >> 4, gio = t & 15;
    int lt2 = (tj0 + gjo) * WW + ti0 + gio;
    int p = gio * 16 + gjo;
    xcTs[(size_t)(cg * 32 + d2) * NR + b * LL + lt2] = sm[p * 35 + d2];
  }
}

// K3a: x_dbl via transposed operands; stride-40 layout, zeroes pad cols 6,7.
__global__ void k_xdbl2(const float* __restrict__ xcT, const float* __restrict__ xcTs,
                        const float* __restrict__ wcatT, float* __restrict__ xdbl) {
  int t = threadIdx.x;
  int rq = blockIdx.x * 256 + t;
  int jg = blockIdx.y;
  int pb = blockIdx.z;
  int p = pb >> 2, b = pb & 3;
  const float4* A = (const float4*)(p ? xcTs : xcT);
  const float* wbase = wcatT + (size_t)p * 192 * 76 + jg * 4;
  float4 acc[4];
#pragma unroll
  for (int j = 0; j < 4; ++j) acc[j] = make_float4(0.f, 0.f, 0.f, 0.f);
  for (int d = 0; d < 192; ++d) {
    float4 xv = A[(size_t)d * (NR / 4) + b * 1024 + rq];
    const float* wr = wbase + d * 76;
#pragma unroll
    for (int j = 0; j < 4; ++j) {
      float w = wr[j];
      acc[j].x += w * xv.x; acc[j].y += w * xv.y;
      acc[j].z += w * xv.z; acc[j].w += w * xv.w;
    }
  }
#pragma unroll
  for (int li = 0; li < 4; ++li) {
    int r = rq * 4 + li;
#pragma unroll
    for (int j = 0; j < 4; ++j) {
      int col = jg * 4 + j;
      int kk = (col >= 38) ? (2 + p) : p;
      int c = (col >= 38) ? col - 38 : col;
      int l = (col >= 38) ? (LL - 1 - r) : r;
      int phys = c + (c >= 6 ? 2 : 0);
      size_t ro = (((size_t)(b * KKv + kk)) * LL + l) * XDS;
      xdbl[ro + phys] = (&acc[j].x)[li];
      if (col == 5) { xdbl[ro + 6] = 0.f; xdbl[ro + 7] = 0.f; }
    }
  }
}

// K4a: chunked scan pass 1. Delta computed in-kernel from staged dt cols.
__global__ void k_scan1(const float* __restrict__ xdbl, const float* __restrict__ xc,
                        const float* __restrict__ alogs, const float* __restrict__ dtw,
                        const float* __restrict__ dtb,
                        float* __restrict__ S, float* __restrict__ P) {
  int bx = blockIdx.x;
  int c = bx / 3, dblk = bx % 3;
  int k = blockIdx.y, b = blockIdx.z;
  int t = threadIdx.x, dl = t >> 2, nq = t & 3;
  int d = dblk * 64 + dl;
  __shared__ float de_s[16][64], xv_s[16][64], bc_s[16][32], dt_s[16][8];
  float A[4];
#pragma unroll
  for (int j = 0; j < 4; ++j)
    A[j] = -__expf(alogs[(size_t)(k * DIv + d) * DSn + nq * 4 + j]);
  int derow = t >> 4, dec0 = (t & 15) * 4;
  float DTW[4][6], DTB[4];
#pragma unroll
  for (int jj = 0; jj < 4; ++jj) {
    int dd = k * DIv + dblk * 64 + dec0 + jj;
    DTB[jj] = dtb[dd];
#pragma unroll
    for (int r2 = 0; r2 < 6; ++r2) DTW[jj][r2] = dtw[(size_t)dd * 6 + r2];
  }
  size_t bkL = (size_t)(b * KKv + k) * LL;
  const float* xq = xdbl + bkL * XDS;
  const float* xcb = xc + (size_t)b * LL * DIv;
  float h[4] = {0.f, 0.f, 0.f, 0.f}, sA[4] = {0.f, 0.f, 0.f, 0.f};
  int l0 = c * CHK;
  for (int tile = 0; tile < CHK / 16; ++tile) {
    int lt = l0 + tile * 16;
    __syncthreads();
    {
      int r = t >> 4, q = t & 15;
      int lc = lmap(k, lt + r);
      *(float4*)&xv_s[r][q * 4] = *(const float4*)(xcb + (size_t)lc * DIv + dblk * 64 + q * 4);
      if (t < 128) {
        int r2 = t >> 3, q2 = t & 7;
        *(float4*)&bc_s[r2][q2 * 4] = *(const float4*)(xq + (size_t)(lt + r2) * XDS + 8 + q2 * 4);
      } else if (t < 160) {
        int i3 = t - 128, r3 = i3 >> 1, half = i3 & 1;
        *(float4*)&dt_s[r3][half * 4] = *(const float4*)(xq + (size_t)(lt + r3) * XDS + half * 4);
      }
    }
    __syncthreads();
    {
#pragma unroll
      for (int jj = 0; jj < 4; ++jj) {
        float s = DTB[jj];
#pragma unroll
        for (int r2 = 0; r2 < 6; ++r2) s += dt_s[derow][r2] * DTW[jj][r2];
        de_s[derow][dec0 + jj] = softp(s);
      }
    }
    __syncthreads();
#pragma unroll
    for (int i2 = 0; i2 < 16; ++i2) {
      float de = de_s[i2][dl];
      float xv = xv_s[i2][dl];
      float4 Bv = *(float4*)&bc_s[i2][nq * 4];
      float db = de * xv;
#pragma unroll
      for (int j = 0; j < 4; ++j) {
        float u = de * A[j];
        sA[j] += u;
        h[j] = h[j] * __expf(u) + db * (&Bv.x)[j];
      }
    }
  }
  size_t o = ((((size_t)(b * KKv + k) * NC + c) * 3 + dblk) * 1024) + (size_t)t * 4;
  float4 hs, ps;
#pragma unroll
  for (int j = 0; j < 4; ++j) { (&hs.x)[j] = h[j]; (&ps.x)[j] = __expf(sA[j]); }
  *(float4*)(S + o) = hs;
  *(float4*)(P + o) = ps;
}

// K4b: sequential chunk combine (float4 per thread). Rewrites S[c] <- Hin[c].
__global__ void k_scan2(float* __restrict__ S, const float* __restrict__ P) {
  int dblk = blockIdx.x, k = blockIdx.y, b = blockIdx.z;
  int t = threadIdx.x;
  size_t base = (((size_t)(b * KKv + k) * NC) * 3 + dblk) * 1024 + (size_t)t * 4;
  float4 h = make_float4(0.f, 0.f, 0.f, 0.f);
  for (int c = 0; c < NC; ++c) {
    size_t o = base + (size_t)c * 3 * 1024;
    float4 s = *(float4*)(S + o), p = *(float4*)(P + o);
    *(float4*)(S + o) = h;
    h.x = s.x + p.x * h.x; h.y = s.y + p.y * h.y;
    h.z = s.z + p.z * h.z; h.w = s.w + p.w * h.w;
  }
}

// K4c: chunked scan pass 3 — delta in-kernel; width-4 shuffle for y.
__global__ void k_scan3(const float* __restrict__ xdbl, const float* __restrict__ xc,
                        const float* __restrict__ alogs, const float* __restrict__ dtw,
                        const float* __restrict__ dtb,
                        const float* __restrict__ Hin, float* __restrict__ ys) {
  int bx = blockIdx.x;
  int c = bx / 3, dblk = bx % 3;
  int k = blockIdx.y, b = blockIdx.z;
  int t = threadIdx.x, dl = t >> 2, nq = t & 3;
  int d = dblk * 64 + dl;
  __shared__ float de_s[16][64], xv_s[16][64], bc_s[16][32], dt_s[16][8];
  float A[4];
#pragma unroll
  for (int j = 0; j < 4; ++j)
    A[j] = -__expf(alogs[(size_t)(k * DIv + d) * DSn + nq * 4 + j]);
  int derow = t >> 4, dec0 = (t & 15) * 4;
  float DTW[4][6], DTB[4];
#pragma unroll
  for (int jj = 0; jj < 4; ++jj) {
    int dd = k * DIv + dblk * 64 + dec0 + jj;
    DTB[jj] = dtb[dd];
#pragma unroll
    for (int r2 = 0; r2 < 6; ++r2) DTW[jj][r2] = dtw[(size_t)dd * 6 + r2];
  }
  size_t bkL = (size_t)(b * KKv + k) * LL;
  const float* xq = xdbl + bkL * XDS;
  const float* xcb = xc + (size_t)b * LL * DIv;
  float* yp = ys + bkL * DIv + d;
  size_t o = ((((size_t)(b * KKv + k) * NC + c) * 3 + dblk) * 1024) + (size_t)t * 4;
  float4 h4 = *(const float4*)(Hin + o);
  float h[4] = {h4.x, h4.y, h4.z, h4.w};
  int l0 = c * CHK;
  for (int tile = 0; tile < CHK / 16; ++tile) {
    int lt = l0 + tile * 16;
    __syncthreads();
    {
      int r = t >> 4, q = t & 15;
      int lc = lmap(k, lt + r);
      *(float4*)&xv_s[r][q * 4] = *(const float4*)(xcb + (size_t)lc * DIv + dblk * 64 + q * 4);
      if (t < 128) {
        int r2 = t >> 3, q2 = t & 7;
        *(float4*)&bc_s[r2][q2 * 4] = *(const float4*)(xq + (size_t)(lt + r2) * XDS + 8 + q2 * 4);
      } else if (t < 160) {
        int i3 = t - 128, r3 = i3 >> 1, half = i3 & 1;
        *(float4*)&dt_s[r3][half * 4] = *(const float4*)(xq + (size_t)(lt + r3) * XDS + half * 4);
      }
    }
    __syncthreads();
    {
#pragma unroll
      for (int jj = 0; jj < 4; ++jj) {
        float s = DTB[jj];
#pragma unroll
        for (int r2 = 0; r2 < 6; ++r2) s += dt_s[derow][r2] * DTW[jj][r2];
        de_s[derow][dec0 + jj] = softp(s);
      }
    }
    __syncthreads();
#pragma unroll
    for (int i2 = 0; i2 < 16; ++i2) {
      float de = de_s[i2][dl];
      float xv = xv_s[i2][dl];
      float4 Bv = *(float4*)&bc_s[i2][nq * 4];
      float4 Cv = *(float4*)&bc_s[i2][16 + nq * 4];
      float db = de * xv;
      float p = 0.f;
#pragma unroll
      for (int j = 0; j < 4; ++j) {
        h[j] = h[j] * __expf(de * A[j]) + db * (&Bv.x)[j];
        p += h[j] * (&Cv.x)[j];
      }
      p += __shfl_down(p, 2, 4);
      p += __shfl_down(p, 1, 4);
      if (nq == 0) yp[(size_t)(lt + i2) * DIv] = p;
    }
  }
}

// K5+K6+transpose fused; also emits row-major bf16 copy ygtB for the MFMA GEMM.
__global__ void k_comlnt(const float* __restrict__ ys, const float* __restrict__ xc,
                         const float* __restrict__ Ds, const float* __restrict__ z,
                         const float* __restrict__ g, const float* __restrict__ be,
                         float* __restrict__ ygtT, __hip_bfloat16* __restrict__ ygtB) {
  int bl0 = blockIdx.x * 32;
  int b = bl0 >> 12, l0 = bl0 & 4095;
  int t = threadIdx.x;              // 256
  __shared__ float vbuf[32 * 193];
  __shared__ float m_[32], rs_[32];
  __shared__ float tile[32][33];
  {
    int grp = t >> 6, lane6 = t & 63;
    size_t base = (size_t)b * KKv * LL * DIv;
#pragma unroll
    for (int i8 = 0; i8 < 8; ++i8) {
      int li = grp + i8 * 4;
      int l = l0 + li;
      int lT = ((l & 63) << 6) | (l >> 6);
      const float* r0 = ys + base + (size_t)l * DIv;
      const float* r2 = ys + base + ((size_t)2 * LL + (LL - 1 - l)) * DIv;
      const float* r1 = ys + base + ((size_t)1 * LL + lT) * DIv;
      const float* r3 = ys + base + ((size_t)3 * LL + (LL - 1 - lT)) * DIv;
      const float* xr = xc + ((size_t)b * LL + l) * DIv;
#pragma unroll
      for (int cc = 0; cc < 3; ++cc) {
        int d = lane6 + cc * 64;
        float sd = Ds[d] + Ds[DIv + d] + Ds[2 * DIv + d] + Ds[3 * DIv + d];
        vbuf[li * 193 + d] = r0[d] + r2[d] + r1[d] + r3[d] + sd * xr[d];
      }
    }
  }
  __syncthreads();
  {
    int r = t >> 3, q = t & 7;
    float s = 0.f, qq = 0.f;
#pragma unroll
    for (int j = 0; j < 24; ++j) {
      float v = vbuf[r * 193 + q + j * 8];
      s += v; qq += v * v;
    }
    s += __shfl_down(s, 4, 8); qq += __shfl_down(qq, 4, 8);
    s += __shfl_down(s, 2, 8); qq += __shfl_down(qq, 2, 8);
    s += __shfl_down(s, 1, 8); qq += __shfl_down(qq, 1, 8);
    if (q == 0) {
      float m = s / DIv;
      m_[r] = m;
      rs_[r] = rsqrtf(qq / DIv - m * m + 1e-5f);
    }
  }
  __syncthreads();
  int tc = t & 31, tr = t >> 5;
  for (int ch = 0; ch < 6; ++ch) {
    int c0 = ch * 32;
    float gg = g[c0 + tc], bb = be[c0 + tc];
    if (ch) __syncthreads();
#pragma unroll
    for (int i = 0; i < 4; ++i) {
      int r = tr + i * 8;
      float v = vbuf[r * 193 + c0 + tc];
      float zz = z[(size_t)(bl0 + r) * DIv + c0 + tc];
      float val = (v - m_[r]) * rs_[r] * gg + bb;
      float gated = val * zz * sigf(zz);
      tile[tc][r] = gated;
      ygtB[(size_t)(bl0 + r) * DIv + c0 + tc] = __float2bfloat16(gated);
    }
    __syncthreads();
#pragma unroll
    for (int i = 0; i < 4; ++i) {
      int cr = tr + i * 8;
      ygtT[(size_t)(c0 + cr) * NR + bl0 + tc] = tile[cr][tc];
    }
  }
}

// K7: out0 = ygated @ out_proj_w.T via ygtT/opwT (fp32, float2 rows, 4 cols).
__global__ void k_outp(const float* __restrict__ ygtT, const float* __restrict__ opwT,
                       float* __restrict__ out0) {
  int t = threadIdx.x;                    // 256
  int r2 = blockIdx.x * 256 + t;
  int c0 = blockIdx.y * 4;
  const float2* x2 = (const float2*)ygtT;
  float2 acc[4];
#pragma unroll
  for (int c = 0; c < 4; ++c) acc[c] = make_float2(0.f, 0.f);
#pragma unroll 4
  for (int k = 0; k < DIv; ++k) {
    float2 xv = x2[(size_t)k * (NR / 2) + r2];
    const float* wr = opwT + k * DMv + c0;  // wave-uniform
#pragma unroll
    for (int c = 0; c < 4; ++c) {
      float w = wr[c];
      acc[c].x += w * xv.x; acc[c].y += w * xv.y;
    }
  }
#pragma unroll
  for (int li = 0; li < 2; ++li) {
    float4 v;
    v.x = (&acc[0].x)[li]; v.y = (&acc[1].x)[li];
    v.z = (&acc[2].x)[li]; v.w = (&acc[3].x)[li];
    *(float4*)(out0 + ((size_t)r2 * 2 + li) * DMv + c0) = v;
  }
}

// K8 (MFMA): hcl = silu(ygated @ ffn_in_w.T + b) in bf16 MFMA, fp32 accumulate.
// Wave = 16 rows x 64 cols; block = 4 waves (64 rows); grid (NR/64, HID/64).
__global__ void k_ffnmf(const __hip_bfloat16* __restrict__ ygtB,
                        const short* __restrict__ fiwP,
                        const float* __restrict__ bias, float* __restrict__ hcl) {
  int t = threadIdx.x;            // 256
  int wv = t >> 6, lane = t & 63;
  int ln16 = lane & 15, qd = lane >> 4;
  int m0 = blockIdx.x * 64 + wv * 16;
  int n0 = blockIdx.y * 64;
  int ntg0 = n0 >> 4;             // first 16-col group
  floatx4 acc[4];
  floatx4 zero4 = {0.f, 0.f, 0.f, 0.f};
#pragma unroll
  for (int nt = 0; nt < 4; ++nt) acc[nt] = zero4;
  const short* arow = (const short*)ygtB + (size_t)(m0 + ln16) * DIv + qd * 8;
#pragma unroll
  for (int kt = 0; kt < 6; ++kt) {
    short8 a = *(const short8*)(arow + kt * 32);
    const short* bb = fiwP + ((size_t)(kt * 48 + ntg0) * 64 + lane) * 8;
#pragma unroll
    for (int nt = 0; nt < 4; ++nt) {
      short8 bfr = *(const short8*)(bb + (size_t)nt * 512);
      acc[nt] = __builtin_amdgcn_mfma_f32_16x16x32_bf16(a, bfr, acc[nt], 0, 0, 0);
    }
  }
  // C/D layout: col = lane&15, row = (lane>>4)*4 + reg  [m89-verified]
#pragma unroll
  for (int nt = 0; nt < 4; ++nt) {
    int col = n0 + nt * 16 + ln16;
    float bv = bias[col];
#pragma unroll
    for (int r = 0; r < 4; ++r) {
      int row = m0 + qd * 4 + r;
      float s = acc[nt][r] + bv;
      hcl[(size_t)row * HIDv + col] = s * sigf(s);
    }
  }
}

// K9: fused 5x5 stencil with sliding 5-row register window.
constexpr int TS = 16, CG = 32, TW = TS + 4;  // TW=20
__global__ void k_ffnconv2(const float* __restrict__ hcl, const float* __restrict__ w1,
                           const float* __restrict__ w3, const float* __restrict__ w5,
                           float* __restrict__ hc2) {
  int tile = blockIdx.x;
  int cg = blockIdx.y, b = blockIdx.z;
  int t = threadIdx.x;
  int ti0 = (tile >> 2) * TS, tj0 = (tile & 3) * TS;
  __shared__ float sm[TW * TW * CG];

  for (int e = t; e < TW * TW * CG; e += 256) {
    int ec = e & 31;
    int sp = e >> 5;
    int hi = sp / TW, hj = sp % TW;
    int gi = ti0 + hi - 2, gj = tj0 + hj - 2;
    float v = 0.f;
    if ((unsigned)gi < (unsigned)HH && (unsigned)gj < (unsigned)WW)
      v = hcl[((size_t)b * LL + gi * WW + gj) * HIDv + cg * CG + ec];
    sm[e] = v;
  }

  int c = t & 31;
  int cglob = cg * CG + c;
  float wc[25];
#pragma unroll
  for (int di = 0; di < 5; ++di)
#pragma unroll
    for (int dj = 0; dj < 5; ++dj) {
      float w = w5[cglob * 25 + di * 5 + dj];
      if (di >= 1 && di <= 3 && dj >= 1 && dj <= 3)
        w += w3[cglob * 9 + (di - 1) * 3 + (dj - 1)];
      if (di == 2 && dj == 2) w += 1.f + w1[cglob];
      wc[di * 5 + dj] = w;
    }
  __syncthreads();

  int q2 = t >> 5;
#pragma unroll
  for (int half = 0; half < 2; ++half) {
    int q = q2 + half * 8;
    float win[5][5];
#pragma unroll
    for (int di = 0; di < 4; ++di)
#pragma unroll
      for (int dj = 0; dj < 5; ++dj)
        win[di][dj] = sm[(di * TW + (q + dj)) * CG + c];
#pragma unroll
    for (int r = 0; r < 16; ++r) {
      int slot = (r + 4) % 5;
#pragma unroll
      for (int dj = 0; dj < 5; ++dj)
        win[slot][dj] = sm[(((r + 4) * TW) + (q + dj)) * CG + c];
      float s = 0.f;
#pragma unroll
      for (int di = 0; di < 5; ++di) {
        int wsl = (r + di) % 5;
#pragma unroll
        for (int dj = 0; dj < 5; ++dj)
          s += win[wsl][dj] * wc[di * 5 + dj];
      }
      hc2[((size_t)b * LL + (ti0 + r) * WW + (tj0 + q)) * HIDv + cglob] = s;
    }
  }
}

// K10: fused LayerNorm(HID) + transpose: hc2[NR][768] -> hnT[768][NR].
__global__ void k_ln2t(const float* __restrict__ hc2, const float* __restrict__ g,
                       const float* __restrict__ be, float* __restrict__ hnT) {
  int r0 = blockIdx.x * 32;
  int t = threadIdx.x;
  __shared__ float m_[32], rs_[32];
  __shared__ float tile[32][33];
  {
    int r = t >> 3, q = t & 7;
    const float4* row4 = (const float4*)(hc2 + (size_t)(r0 + r) * HIDv);
    float s = 0.f, qq = 0.f;
#pragma unroll
    for (int j = 0; j < 24; ++j) {
      float4 v = row4[q + j * 8];
      s += v.x + v.y + v.z + v.w;
      qq += v.x * v.x + v.y * v.y + v.z * v.z + v.w * v.w;
    }
    s += __shfl_down(s, 4, 8); qq += __shfl_down(qq, 4, 8);
    s += __shfl_down(s, 2, 8); qq += __shfl_down(qq, 2, 8);
    s += __shfl_down(s, 1, 8); qq += __shfl_down(qq, 1, 8);
    if (q == 0) {
      float m = s / HIDv;
      m_[r] = m;
      rs_[r] = rsqrtf(qq / HIDv - m * m + 1e-5f);
    }
  }
  __syncthreads();
  int tc = t & 31, tr = t >> 5;
  for (int ch = 0; ch < 24; ++ch) {
    int c0 = ch * 32;
    float gg = g[c0 + tc], bb = be[c0 + tc];
    if (ch) __syncthreads();
#pragma unroll
    for (int i = 0; i < 4; ++i) {
      int r = tr + i * 8;
      float v = hc2[(size_t)(r0 + r) * HIDv + c0 + tc];
      tile[tc][r] = (v - m_[r]) * rs_[r] * gg + bb;
    }
    __syncthreads();
#pragma unroll
    for (int i = 0; i < 4; ++i) {
      int cr = tr + i * 8;
      hnT[(size_t)(c0 + cr) * NR + r0 + tc] = tile[cr][tc];
    }
  }
}

// K11a: split-K partial GEMM: part[ks][row][c] = sum_{k in seg} hnT*fowT.
__global__ void k_final3(const float* __restrict__ hnT, const float* __restrict__ fowT,
                         float* __restrict__ part) {
  int t = threadIdx.x;                    // 128
  int rq = blockIdx.x * 128 + t;
  int c0 = blockIdx.y * 8;
  int ks = blockIdx.z;
  const float4* x4 = (const float4*)hnT;
  float4 acc[8];
#pragma unroll
  for (int c = 0; c < 8; ++c) acc[c] = make_float4(0.f, 0.f, 0.f, 0.f);
  int k0 = ks * 192;
#pragma unroll 4
  for (int k = k0; k < k0 + 192; ++k) {
    float4 xv = x4[(size_t)k * (NR / 4) + rq];
    const float* wr = fowT + k * DMv + c0;
#pragma unroll
    for (int c = 0; c < 8; ++c) {
      float w = wr[c];
      acc[c].x += w * xv.x; acc[c].y += w * xv.y;
      acc[c].z += w * xv.z; acc[c].w += w * xv.w;
    }
  }
  float* pb = part + (size_t)ks * NR * DMv;
#pragma unroll
  for (int li = 0; li < 4; ++li) {
    size_t row = (size_t)rq * 4 + li;
#pragma unroll
    for (int cc = 0; cc < 2; ++cc) {
      float4 v;
#pragma unroll
      for (int j = 0; j < 4; ++j) (&v.x)[j] = (&acc[cc * 4 + j].x)[li];
      *(float4*)(pb + row * DMv + c0 + cc * 4) = v;
    }
  }
}

// K11b: dout = out0 + skip*(sum_k part[k] + bias), float4 elementwise.
__global__ void k_finred(const float* __restrict__ part, const float* __restrict__ out0,
                         const float* __restrict__ bias, const float* __restrict__ skip,
                         float* __restrict__ dout) {
  size_t i = (size_t)blockIdx.x * 256 + threadIdx.x;
  int cq = (int)(i % (DMv / 4));
  const float4* p4 = (const float4*)part;
  size_t npart = (size_t)NR * DMv / 4;
  float4 a = p4[i], b2 = p4[i + npart], c2 = p4[i + 2 * npart], d2 = p4[i + 3 * npart];
  float4 o = ((const float4*)out0)[i];
  float4 bi = ((const float4*)bias)[cq];
  float sk = skip[0];
  float4 r;
  r.x = o.x + sk * (a.x + b2.x + c2.x + d2.x + bi.x);
  r.y = o.y + sk * (a.y + b2.y + c2.y + d2.y + bi.y);
  r.z = o.z + sk * (a.z + b2.z + c2.z + d2.z + bi.z);
  r.w = o.w + sk * (a.w + b2.w + c2.w + d2.w + bi.w);
  ((float4*)dout)[i] = r;
}

extern "C" void kernel_launch(void* const* d_in, const int* in_sizes, int n_in,
                              void* d_out, int out_size, void* d_ws, size_t ws_size,
                              hipStream_t stream) {
  const float* x        = (const float*)d_in[0];
  const float* in_w     = (const float*)d_in[1];
  const float* conv_w   = (const float*)d_in[2];
  const float* conv_b   = (const float*)d_in[3];
  const float* xpw      = (const float*)d_in[4];
  const float* dtw      = (const float*)d_in[5];
  const float* dtb      = (const float*)d_in[6];
  const float* alogs    = (const float*)d_in[7];
  const float* Ds       = (const float*)d_in[8];
  const float* ong      = (const float*)d_in[9];
  const float* onb      = (const float*)d_in[10];
  const float* opw      = (const float*)d_in[11];
  const float* fiw      = (const float*)d_in[12];
  const float* fib      = (const float*)d_in[13];
  const float* dw1      = (const float*)d_in[14];
  const float* dw3      = (const float*)d_in[15];
  const float* dw5      = (const float*)d_in[16];
  const float* flg      = (const float*)d_in[17];
  const float* flb      = (const float*)d_in[18];
  const float* fow      = (const float*)d_in[19];
  const float* fob      = (const float*)d_in[20];
  const float* skip     = (const float*)d_in[21];

  // Workspace layout (aliased; ~157 MB)
  float* ws    = (float*)d_ws;
  float* xi    = ws;                 // -> S/P -> ygtT -> part (with z)
  float* z     = xi + S_xi;
  float* xc    = z + S_xi;
  float* xdbl  = xc + S_xi;          // -> out0
  float* scr   = xdbl + S_xdbl;      // xt scratch -> hcl -> hnT
  float* ys    = scr + S_big;        // xcT/xcTs -> ys -> hc2
  float* wtiny = ys + S_big;         // persistent small buffers
  float* fiwT  = wtiny;              // 147456
  float* opwT  = fiwT + 147456;      // 18432
  float* fowT  = opwT + 18432;       // 73728
  float* wcatT = fowT + 73728;       // 29184
  float* wt    = wcatT + 29184;      // 36864
  __hip_bfloat16* ygtB = (__hip_bfloat16*)(wt + 36864);   // NR*192 bf16 = 1,572,864 floats
  short* fiwP  = (short*)((float*)(wt + 36864) + 1572864); // 288*512 shorts (after FULL ygtB)

  // Merged weight prep + xt transpose + fiwP packing (1 dispatch, 1224 blocks)
  float* xt = scr;
  k_wprep<<<1224, 256, 0, stream>>>(fiw, opw, fow, in_w, xpw, x,
                                    fiwT, opwT, fowT, wt, wcatT, xt, fiwP);

  dim3 gip(NR / 1024, 48);
  k_inproj<<<gip, 256, 0, stream>>>(xt, wt, xi, z);

  // Fused dwconv + 3-layout emit (xc, xcT, xcTs)
  float* xcT  = ys;
  float* xcTs = ys + S_xi;
  dim3 gdw(16, DIv / 32, BB);
  k_dwconv3<<<gdw, 256, 0, stream>>>(xi, conv_w, conv_b, xc, xcT, xcTs);

  dim3 gxd(4, 19, 8);
  k_xdbl2<<<gxd, 256, 0, stream>>>(xcT, xcTs, wcatT, xdbl);

  // Chunked scan (delta fused in): S/P alias xi
  float* Sbuf = xi;
  float* Pbuf = xi + S_sp;
  dim3 gs13(NC * 3, KKv, BB);
  dim3 gs2(3, KKv, BB);
  k_scan1<<<gs13, 256, 0, stream>>>(xdbl, xc, alogs, dtw, dtb, Sbuf, Pbuf);
  k_scan2<<<gs2, 256, 0, stream>>>(Sbuf, Pbuf);
  k_scan3<<<gs13, 256, 0, stream>>>(xdbl, xc, alogs, dtw, dtb, Sbuf, ys);

  // Fused combine + LN + silu-gate + transpose; emits ygtT (f32) and ygtB (bf16)
  float* ygtT = xi;
  k_comlnt<<<NR / 32, 256, 0, stream>>>(ys, xc, Ds, z, ong, onb, ygtT, ygtB);

  // out_proj (fp32) + ffn_in (bf16 MFMA)
  float* out0 = xdbl;
  float* hcl = scr;
  dim3 gop(NR / 512, DMv / 4);       // (32, 24)
  k_outp<<<gop, 256, 0, stream>>>(ygtT, opwT, out0);
  dim3 gmf(NR / 64, HIDv / 64);      // (256, 12) = 3072 blocks
  k_ffnmf<<<gmf, 256, 0, stream>>>(ygtB, fiwP, fib, hcl);

  float* hc2 = ys;
  dim3 gc(16, HIDv / CG, BB);
  k_ffnconv2<<<gc, 256, 0, stream>>>(hcl, dw1, dw3, dw5, hc2);

  // Fused LayerNorm + transpose: hc2 -> hnT
  float* hnT = scr;
  k_ln2t<<<NR / 32, 256, 0, stream>>>(hc2, flg, flb, hnT);

  // Split-K final GEMM
  float* part = xi;
  dim3 gfn(NR / 512, DMv / 8, 4);
  k_final3<<<gfn, 128, 0, stream>>>(hnT, fowT, part);
  k_finred<<<(NR * DMv / 4) / 256, 256, 0, stream>>>(part, out0, fob, skip, (float*)d_out);
}